// Round 1
// baseline (254.327 us; speedup 1.0000x reference)
//
#include <hip/hip_runtime.h>
#include <hip/hip_bf16.h>

#define NN 512
#define NH 64
#define MAXD 96      // neighbor-list capacity (binomial mean 32, +10 sigma safe)
#define CHUNK 128    // k-rows per hid block

// ---------------- ws layout (bytes) ----------------
// nbr16 : NN*MAXD*2 = 98304   @ 0        sorted neighbor lists, 0xFFFF sentinel pad
// cnt   : NN*4      = 2048    @ 98304
// base  : NN*NH*4   = 131072  @ 100352   z @ W1[:256]
// degt  : NN*NN*2   = 524288  @ 231424   bf16 deg[i][c]
// hidt  : NN*NN*2   = 524288  @ 755712   bf16 hid[i][k] (valid k<i only)
// total = 1280000

// Build sorted neighbor lists per column (adj symmetric). Coalesced row sweeps.
__global__ __launch_bounds__(64) void build_lists(const float* __restrict__ adj,
                                                  unsigned short* __restrict__ nbr,
                                                  int* __restrict__ cnt) {
    int c = blockIdx.x * 64 + threadIdx.x;
    unsigned short* row = nbr + c * MAXD;
    int n = 0;
    for (int r = 0; r < NN; ++r) {
        float v = adj[r * NN + c];
        if (v != 0.0f) { if (n < MAXD) row[n] = (unsigned short)r; ++n; }
    }
    int m = n < MAXD ? n : MAXD;
    cnt[c] = m;
    for (int j = m; j < MAXD; ++j) row[j] = 0xFFFFu;  // sentinel > any i
}

// deg[i][c] = rsqrt(max(#neighbors of c below i, 1)). Branchless count over padded list.
__global__ __launch_bounds__(NN) void build_deg(const unsigned short* __restrict__ nbr,
                                                __hip_bfloat16* __restrict__ degt) {
    int i = blockIdx.x, c = threadIdx.x;
    const uint4* lst = (const uint4*)(nbr + c * MAXD);
    int p = 0;
    #pragma unroll
    for (int b = 0; b < MAXD / 8; ++b) {
        uint4 q = lst[b];
        unsigned v[4] = {q.x, q.y, q.z, q.w};
        #pragma unroll
        for (int t = 0; t < 4; ++t) {
            p += ((v[t] & 0xFFFFu) < (unsigned)i);
            p += ((v[t] >> 16)     < (unsigned)i);
        }
    }
    float d = rsqrtf((float)(p > 0 ? p : 1));
    degt[i * NN + c] = __float2bfloat16(d);
}

// base = z[512,256] @ W1[0:256, 0:64].  8 blocks x 64 rows, 16x16 threads, 4x4 micro.
__global__ __launch_bounds__(256) void gemm_base(const float* __restrict__ z,
                                                 const float* __restrict__ W1,
                                                 float* __restrict__ base) {
    __shared__ float As[16][68];
    __shared__ float Bsh[16][68];
    const int bi = blockIdx.x;
    const int tid = threadIdx.x, tx = tid & 15, ty = tid >> 4;
    float acc[4][4] = {};
    for (int kk = 0; kk < 256; kk += 16) {
        #pragma unroll
        for (int l = 0; l < 4; ++l) {
            int id = tid + (l << 8);
            int m = id >> 4, k = id & 15;
            As[k][m] = z[(bi * 64 + m) * 256 + kk + k];
        }
        #pragma unroll
        for (int l = 0; l < 4; ++l) {
            int id = tid + (l << 8);
            int k = id >> 6, n2 = id & 63;
            Bsh[k][n2] = W1[(kk + k) * 64 + n2];
        }
        __syncthreads();
        #pragma unroll
        for (int k = 0; k < 16; ++k) {
            float4 a = *(const float4*)&As[k][ty * 4];
            float4 b = *(const float4*)&Bsh[k][tx * 4];
            float ar[4] = {a.x, a.y, a.z, a.w};
            float br[4] = {b.x, b.y, b.z, b.w};
            #pragma unroll
            for (int p = 0; p < 4; ++p)
                #pragma unroll
                for (int q = 0; q < 4; ++q)
                    acc[p][q] = fmaf(ar[p], br[q], acc[p][q]);
        }
        __syncthreads();
    }
    #pragma unroll
    for (int p = 0; p < 4; ++p) {
        float4 st = make_float4(acc[p][0], acc[p][1], acc[p][2], acc[p][3]);
        *(float4*)&base[(bi * 64 + ty * 4 + p) * NH + tx * 4] = st;
    }
}

// out = z @ z^T.  (8,8) blocks of 64x64.
__global__ __launch_bounds__(256) void gemm_x(const float* __restrict__ z,
                                              float* __restrict__ out) {
    __shared__ float As[16][68];
    __shared__ float Bsh[16][68];
    const int bi = blockIdx.y, bj = blockIdx.x;
    const int tid = threadIdx.x, tx = tid & 15, ty = tid >> 4;
    float acc[4][4] = {};
    for (int kk = 0; kk < 256; kk += 16) {
        #pragma unroll
        for (int l = 0; l < 4; ++l) {
            int id = tid + (l << 8);
            int m = id >> 4, k = id & 15;
            As[k][m]  = z[(bi * 64 + m) * 256 + kk + k];
            Bsh[k][m] = z[(bj * 64 + m) * 256 + kk + k];
        }
        __syncthreads();
        #pragma unroll
        for (int k = 0; k < 16; ++k) {
            float4 a = *(const float4*)&As[k][ty * 4];
            float4 b = *(const float4*)&Bsh[k][tx * 4];
            float ar[4] = {a.x, a.y, a.z, a.w};
            float br[4] = {b.x, b.y, b.z, b.w};
            #pragma unroll
            for (int p = 0; p < 4; ++p)
                #pragma unroll
                for (int q = 0; q < 4; ++q)
                    acc[p][q] = fmaf(ar[p], br[q], acc[p][q]);
        }
        __syncthreads();
    }
    #pragma unroll
    for (int p = 0; p < 4; ++p) {
        float4 st = make_float4(acc[p][0], acc[p][1], acc[p][2], acc[p][3]);
        *(float4*)&out[(bi * 64 + ty * 4 + p) * NN + bj * 64 + tx * 4] = st;
    }
}

// hid[i][k] = sum_h relu(deg_i[k] * sum_{l in nbr(k), l<i} deg_i[l]*base[l][h]) * W2[h]
// One block per (i, 128-k chunk). g[l][h] = deg_i[l]*base[l][h] staged bf16 in LDS,
// zero rows for l>=i; sentinel indices clamp to row 511 (always zero). Branchless.
__global__ __launch_bounds__(512) void hid_kernel(const unsigned short* __restrict__ nbr,
                                                  const int* __restrict__ cnt,
                                                  const float* __restrict__ base,
                                                  const __hip_bfloat16* __restrict__ degt,
                                                  const float* __restrict__ W2,
                                                  __hip_bfloat16* __restrict__ hidt) {
    __shared__ __hip_bfloat16 g[NN * NH];   // 64 KB
    __shared__ float degl[NN];
    const int i  = 511 - (int)blockIdx.y;   // big blocks dispatch first
    const int cb = blockIdx.x * CHUNK;
    if (cb >= i) return;
    const int tid = threadIdx.x;
    degl[tid] = __bfloat162float(degt[i * NN + tid]);
    __syncthreads();
    for (int t = tid; t < NN * NH; t += 512) {
        int l = t >> 6;
        float v = (l < i) ? degl[l] * base[t] : 0.0f;
        g[t] = __float2bfloat16(v);
    }
    __syncthreads();
    const int lane = tid & 63, w = tid >> 6;
    const float w2 = W2[lane];
    for (int t = 0; t < 16; ++t) {
        int k = cb + w * 16 + t;
        if (k >= i) continue;               // uniform per wave
        const uint4* lst = (const uint4*)(nbr + k * MAXD);
        int nb = (cnt[k] + 7) >> 3;
        float acc = 0.0f;
        for (int b = 0; b < nb; ++b) {
            uint4 q = lst[b];
            unsigned rr[8] = {q.x & 0xFFFFu, q.x >> 16, q.y & 0xFFFFu, q.y >> 16,
                              q.z & 0xFFFFu, q.z >> 16, q.w & 0xFFFFu, q.w >> 16};
            #pragma unroll
            for (int e = 0; e < 8; ++e) {
                unsigned r = rr[e] < (NN - 1u) ? rr[e] : (NN - 1u);
                acc += __bfloat162float(g[(r << 6) + lane]);
            }
        }
        float val = degl[k] * acc;
        val = fmaxf(val, 0.0f) * w2;
        #pragma unroll
        for (int off = 32; off; off >>= 1) val += __shfl_xor(val, off, 64);
        if (lane == 0) hidt[i * NN + k] = __float2bfloat16(val);
    }
}

// s[i][j] = 0.5*deg_i[j]*sum_{k in nbr(j), k<i} deg_i[k]*hid[i][k]; out[i][j]+=s, out[j][i]+=s
__global__ __launch_bounds__(NN) void supp_kernel(const unsigned short* __restrict__ nbr,
                                                  const int* __restrict__ cnt,
                                                  const __hip_bfloat16* __restrict__ degt,
                                                  const __hip_bfloat16* __restrict__ hidt,
                                                  float* __restrict__ out) {
    __shared__ float degl[NN];
    __shared__ float hidl[NN];
    const int i = 511 - (int)blockIdx.x;
    if (i < 1) return;
    const int tid = threadIdx.x;
    degl[tid] = __bfloat162float(degt[i * NN + tid]);
    hidl[tid] = (tid < i) ? __bfloat162float(hidt[i * NN + tid]) : 0.0f;
    __syncthreads();
    const int j = tid;
    if (j >= i) return;
    const uint4* lst = (const uint4*)(nbr + j * MAXD);
    int nb = (cnt[j] + 7) >> 3;
    float s = 0.0f;
    for (int b = 0; b < nb; ++b) {
        uint4 q = lst[b];
        unsigned rr[8] = {q.x & 0xFFFFu, q.x >> 16, q.y & 0xFFFFu, q.y >> 16,
                          q.z & 0xFFFFu, q.z >> 16, q.w & 0xFFFFu, q.w >> 16};
        #pragma unroll
        for (int e = 0; e < 8; ++e) {
            unsigned r = rr[e] < (NN - 1u) ? rr[e] : (NN - 1u);
            s += degl[r] * hidl[r];
        }
    }
    s *= 0.5f * degl[j];
    out[i * NN + j] += s;
    out[j * NN + i] += s;
}

extern "C" void kernel_launch(void* const* d_in, const int* in_sizes, int n_in,
                              void* d_out, int out_size, void* d_ws, size_t ws_size,
                              hipStream_t stream) {
    const float* z   = (const float*)d_in[0];
    const float* adj = (const float*)d_in[1];
    const float* W1  = (const float*)d_in[2];
    const float* W2  = (const float*)d_in[3];
    float* out = (float*)d_out;

    char* w = (char*)d_ws;
    unsigned short* nbr  = (unsigned short*)(w + 0);
    int*            cnt  = (int*)           (w + 98304);
    float*          base = (float*)         (w + 100352);
    __hip_bfloat16* degt = (__hip_bfloat16*)(w + 231424);
    __hip_bfloat16* hidt = (__hip_bfloat16*)(w + 755712);

    build_lists<<<8, 64, 0, stream>>>(adj, nbr, cnt);
    build_deg<<<NN, NN, 0, stream>>>(nbr, degt);
    gemm_base<<<8, 256, 0, stream>>>(z, W1, base);
    hid_kernel<<<dim3(NN / CHUNK, NN), 512, 0, stream>>>(nbr, cnt, base, degt, W2, hidt);
    gemm_x<<<dim3(8, 8), 256, 0, stream>>>(z, out);
    supp_kernel<<<NN, NN, 0, stream>>>(nbr, cnt, degt, hidt, out);
}

// Round 2
// 177.704 us; speedup vs baseline: 1.4312x; 1.4312x over previous
//
#include <hip/hip_runtime.h>
#include <hip/hip_bf16.h>

#define NN 512
#define NH 64
#define MAXD 96      // neighbor-list capacity (binomial mean 32, +10 sigma safe)
#define CHUNK 128    // k-rows per hid block

// ---------------- ws layout (bytes) ----------------
// nbr16 : NN*MAXD*2 = 98304   @ 0        sorted neighbor lists, 0xFFFF sentinel pad
// cnt   : NN*4      = 2048    @ 98304
// base  : NN*NH*4   = 131072  @ 100352   z @ W1[:256]
// degt  : NN*NN*2   = 524288  @ 231424   bf16 deg[i][c]
// hidt  : NN*NN*2   = 524288  @ 755712   bf16 hid[i][k] (valid k<i only)
// total = 1280000

// adj is symmetric => column c's nonzeros == row c's nonzeros. One block per
// column, coalesced row read, ballot + wave-count prefix to compact in order.
__global__ __launch_bounds__(512) void build_lists(const float* __restrict__ adj,
                                                   unsigned short* __restrict__ nbr,
                                                   int* __restrict__ cnt) {
    const int c = blockIdx.x;
    const int r = threadIdx.x;
    const int lane = r & 63, w = r >> 6;
    __shared__ int wcnt[8];
    float v = adj[c * NN + r];              // row c == column c (symmetric)
    bool f = (v != 0.0f);
    unsigned long long m = __ballot(f);
    int before = __popcll(m & ((1ull << lane) - 1ull));
    if (lane == 0) wcnt[w] = __popcll(m);
    __syncthreads();
    int pre = 0, total = 0;
    #pragma unroll
    for (int t = 0; t < 8; ++t) {
        int x = wcnt[t];
        pre += (t < w) ? x : 0;
        total += x;
    }
    unsigned short* row = nbr + c * MAXD;
    int pos = pre + before;
    if (f && pos < MAXD) row[pos] = (unsigned short)r;
    int mcnt = total < MAXD ? total : MAXD;
    if (r == 0) cnt[c] = mcnt;
    for (int j = mcnt + r; j < MAXD; j += 512) row[j] = 0xFFFFu;  // sentinel pad
}

// deg[i][c] = rsqrt(max(#neighbors of c below i, 1)). Branchless count over padded list.
__global__ __launch_bounds__(NN) void build_deg(const unsigned short* __restrict__ nbr,
                                                __hip_bfloat16* __restrict__ degt) {
    int i = blockIdx.x, c = threadIdx.x;
    const uint4* lst = (const uint4*)(nbr + c * MAXD);
    int p = 0;
    #pragma unroll
    for (int b = 0; b < MAXD / 8; ++b) {
        uint4 q = lst[b];
        unsigned v[4] = {q.x, q.y, q.z, q.w};
        #pragma unroll
        for (int t = 0; t < 4; ++t) {
            p += ((v[t] & 0xFFFFu) < (unsigned)i);
            p += ((v[t] >> 16)     < (unsigned)i);
        }
    }
    float d = rsqrtf((float)(p > 0 ? p : 1));
    degt[i * NN + c] = __float2bfloat16(d);
}

// base = z[512,256] @ W1[0:256, 0:64].  8 blocks x 64 rows, 16x16 threads, 4x4 micro.
__global__ __launch_bounds__(256) void gemm_base(const float* __restrict__ z,
                                                 const float* __restrict__ W1,
                                                 float* __restrict__ base) {
    __shared__ float As[16][68];
    __shared__ float Bsh[16][68];
    const int bi = blockIdx.x;
    const int tid = threadIdx.x, tx = tid & 15, ty = tid >> 4;
    float acc[4][4] = {};
    for (int kk = 0; kk < 256; kk += 16) {
        #pragma unroll
        for (int l = 0; l < 4; ++l) {
            int id = tid + (l << 8);
            int m = id >> 4, k = id & 15;
            As[k][m] = z[(bi * 64 + m) * 256 + kk + k];
        }
        #pragma unroll
        for (int l = 0; l < 4; ++l) {
            int id = tid + (l << 8);
            int k = id >> 6, n2 = id & 63;
            Bsh[k][n2] = W1[(kk + k) * 64 + n2];
        }
        __syncthreads();
        #pragma unroll
        for (int k = 0; k < 16; ++k) {
            float4 a = *(const float4*)&As[k][ty * 4];
            float4 b = *(const float4*)&Bsh[k][tx * 4];
            float ar[4] = {a.x, a.y, a.z, a.w};
            float br[4] = {b.x, b.y, b.z, b.w};
            #pragma unroll
            for (int p = 0; p < 4; ++p)
                #pragma unroll
                for (int q = 0; q < 4; ++q)
                    acc[p][q] = fmaf(ar[p], br[q], acc[p][q]);
        }
        __syncthreads();
    }
    #pragma unroll
    for (int p = 0; p < 4; ++p) {
        float4 st = make_float4(acc[p][0], acc[p][1], acc[p][2], acc[p][3]);
        *(float4*)&base[(bi * 64 + ty * 4 + p) * NH + tx * 4] = st;
    }
}

// out = z @ z^T.  (8,8) blocks of 64x64.
__global__ __launch_bounds__(256) void gemm_x(const float* __restrict__ z,
                                              float* __restrict__ out) {
    __shared__ float As[16][68];
    __shared__ float Bsh[16][68];
    const int bi = blockIdx.y, bj = blockIdx.x;
    const int tid = threadIdx.x, tx = tid & 15, ty = tid >> 4;
    float acc[4][4] = {};
    for (int kk = 0; kk < 256; kk += 16) {
        #pragma unroll
        for (int l = 0; l < 4; ++l) {
            int id = tid + (l << 8);
            int m = id >> 4, k = id & 15;
            As[k][m]  = z[(bi * 64 + m) * 256 + kk + k];
            Bsh[k][m] = z[(bj * 64 + m) * 256 + kk + k];
        }
        __syncthreads();
        #pragma unroll
        for (int k = 0; k < 16; ++k) {
            float4 a = *(const float4*)&As[k][ty * 4];
            float4 b = *(const float4*)&Bsh[k][tx * 4];
            float ar[4] = {a.x, a.y, a.z, a.w};
            float br[4] = {b.x, b.y, b.z, b.w};
            #pragma unroll
            for (int p = 0; p < 4; ++p)
                #pragma unroll
                for (int q = 0; q < 4; ++q)
                    acc[p][q] = fmaf(ar[p], br[q], acc[p][q]);
        }
        __syncthreads();
    }
    #pragma unroll
    for (int p = 0; p < 4; ++p) {
        float4 st = make_float4(acc[p][0], acc[p][1], acc[p][2], acc[p][3]);
        *(float4*)&out[(bi * 64 + ty * 4 + p) * NN + bj * 64 + tx * 4] = st;
    }
}

// hid[i][k] = sum_h relu(deg_i[k] * sum_{l in nbr(k), l<i} deg_i[l]*base[l][h]) * W2[h]
// One block per (i, 128-k chunk). g[l][h] = deg_i[l]*base[l][h] staged bf16 in LDS,
// zero rows for l>=i; sentinel indices clamp to row 511 (always zero). Branchless.
__global__ __launch_bounds__(512) void hid_kernel(const unsigned short* __restrict__ nbr,
                                                  const int* __restrict__ cnt,
                                                  const float* __restrict__ base,
                                                  const __hip_bfloat16* __restrict__ degt,
                                                  const float* __restrict__ W2,
                                                  __hip_bfloat16* __restrict__ hidt) {
    __shared__ __hip_bfloat16 g[NN * NH];   // 64 KB
    __shared__ float degl[NN];
    const int i  = 511 - (int)blockIdx.y;   // big blocks dispatch first
    const int cb = blockIdx.x * CHUNK;
    if (cb >= i) return;
    const int tid = threadIdx.x;
    degl[tid] = __bfloat162float(degt[i * NN + tid]);
    __syncthreads();
    for (int t = tid; t < NN * NH; t += 512) {
        int l = t >> 6;
        float v = (l < i) ? degl[l] * base[t] : 0.0f;
        g[t] = __float2bfloat16(v);
    }
    __syncthreads();
    const int lane = tid & 63, w = tid >> 6;
    const float w2 = W2[lane];
    for (int t = 0; t < 16; ++t) {
        int k = cb + w * 16 + t;
        if (k >= i) continue;               // uniform per wave
        const uint4* lst = (const uint4*)(nbr + k * MAXD);
        int nb = (cnt[k] + 7) >> 3;
        float acc = 0.0f;
        for (int b = 0; b < nb; ++b) {
            uint4 q = lst[b];
            unsigned rr[8] = {q.x & 0xFFFFu, q.x >> 16, q.y & 0xFFFFu, q.y >> 16,
                              q.z & 0xFFFFu, q.z >> 16, q.w & 0xFFFFu, q.w >> 16};
            #pragma unroll
            for (int e = 0; e < 8; ++e) {
                unsigned r = rr[e] < (NN - 1u) ? rr[e] : (NN - 1u);
                acc += __bfloat162float(g[(r << 6) + lane]);
            }
        }
        float val = degl[k] * acc;
        val = fmaxf(val, 0.0f) * w2;
        #pragma unroll
        for (int off = 32; off; off >>= 1) val += __shfl_xor(val, off, 64);
        if (lane == 0) hidt[i * NN + k] = __float2bfloat16(val);
    }
}

// s[i][j] = 0.5*deg_i[j]*sum_{k in nbr(j), k<i} deg_i[k]*hid[i][k]; out[i][j]+=s, out[j][i]+=s
__global__ __launch_bounds__(NN) void supp_kernel(const unsigned short* __restrict__ nbr,
                                                  const int* __restrict__ cnt,
                                                  const __hip_bfloat16* __restrict__ degt,
                                                  const __hip_bfloat16* __restrict__ hidt,
                                                  float* __restrict__ out) {
    __shared__ float degl[NN];
    __shared__ float hidl[NN];
    const int i = 511 - (int)blockIdx.x;
    if (i < 1) return;
    const int tid = threadIdx.x;
    degl[tid] = __bfloat162float(degt[i * NN + tid]);
    hidl[tid] = (tid < i) ? __bfloat162float(hidt[i * NN + tid]) : 0.0f;
    __syncthreads();
    const int j = tid;
    if (j >= i) return;
    const uint4* lst = (const uint4*)(nbr + j * MAXD);
    int nb = (cnt[j] + 7) >> 3;
    float s = 0.0f;
    for (int b = 0; b < nb; ++b) {
        uint4 q = lst[b];
        unsigned rr[8] = {q.x & 0xFFFFu, q.x >> 16, q.y & 0xFFFFu, q.y >> 16,
                          q.z & 0xFFFFu, q.z >> 16, q.w & 0xFFFFu, q.w >> 16};
        #pragma unroll
        for (int e = 0; e < 8; ++e) {
            unsigned r = rr[e] < (NN - 1u) ? rr[e] : (NN - 1u);
            s += degl[r] * hidl[r];
        }
    }
    s *= 0.5f * degl[j];
    out[i * NN + j] += s;
    out[j * NN + i] += s;
}

extern "C" void kernel_launch(void* const* d_in, const int* in_sizes, int n_in,
                              void* d_out, int out_size, void* d_ws, size_t ws_size,
                              hipStream_t stream) {
    const float* z   = (const float*)d_in[0];
    const float* adj = (const float*)d_in[1];
    const float* W1  = (const float*)d_in[2];
    const float* W2  = (const float*)d_in[3];
    float* out = (float*)d_out;

    char* w = (char*)d_ws;
    unsigned short* nbr  = (unsigned short*)(w + 0);
    int*            cnt  = (int*)           (w + 98304);
    float*          base = (float*)         (w + 100352);
    __hip_bfloat16* degt = (__hip_bfloat16*)(w + 231424);
    __hip_bfloat16* hidt = (__hip_bfloat16*)(w + 755712);

    build_lists<<<NN, 512, 0, stream>>>(adj, nbr, cnt);
    build_deg<<<NN, NN, 0, stream>>>(nbr, degt);
    gemm_base<<<8, 256, 0, stream>>>(z, W1, base);
    hid_kernel<<<dim3(NN / CHUNK, NN), 512, 0, stream>>>(nbr, cnt, base, degt, W2, hidt);
    gemm_x<<<dim3(8, 8), 256, 0, stream>>>(z, out);
    supp_kernel<<<NN, NN, 0, stream>>>(nbr, cnt, degt, hidt, out);
}

// Round 3
// 116.709 us; speedup vs baseline: 2.1791x; 1.5226x over previous
//
#include <hip/hip_runtime.h>
#include <hip/hip_bf16.h>

#define NN 512
#define NH 64
#define MAXD 80          // binomial(511,1/16): mean 32, sigma 5.5 -> 80 = +8.7 sigma
#define ZOFF (511 * 64)  // sentinel entry -> row 511 of g2, kept all-zero

// ---------------- ws layout (bytes) ----------------
// nbr32 : NN*MAXD*4 = 163840 @ 0        entries = r*64 (element offset), sentinel ZOFF
// base  : NN*NH*4   = 131072 @ 163840   z @ W1[:256]
// degt  : NN*NN*2   = 524288 @ 294912   bf16 deg[i][c]
// pcnt  : NN*NN*1   = 262144 @ 819200   u8  #{l in nbr(c): l < i}
// total = 1081344

// adj symmetric => column c nonzeros == row c nonzeros. Coalesced row read,
// ballot + per-wave prefix compaction (order-preserving => sorted lists).
__global__ __launch_bounds__(512) void build_lists(const float* __restrict__ adj,
                                                   unsigned* __restrict__ nbr) {
    const int c = blockIdx.x;
    const int r = threadIdx.x;
    const int lane = r & 63, w = r >> 6;
    __shared__ int wcnt[8];
    bool f = (adj[c * NN + r] != 0.0f);
    unsigned long long m = __ballot(f);
    int before = __popcll(m & ((1ull << lane) - 1ull));
    if (lane == 0) wcnt[w] = __popcll(m);
    __syncthreads();
    int pre = 0, total = 0;
    #pragma unroll
    for (int t = 0; t < 8; ++t) {
        int x = wcnt[t];
        pre += (t < w) ? x : 0;
        total += x;
    }
    unsigned* row = nbr + c * MAXD;
    int pos = pre + before;
    if (f && pos < MAXD) row[pos] = (unsigned)(r * 64);
    int m2 = total < MAXD ? total : MAXD;
    for (int j = m2 + r; j < MAXD; j += 512) row[j] = ZOFF;
}

// deg[i][c] = rsqrt(max(p,1)), pcnt[i][c] = p = #entries < i*64 (lists sorted).
__global__ __launch_bounds__(NN) void build_deg(const unsigned* __restrict__ nbr,
                                                __hip_bfloat16* __restrict__ degt,
                                                unsigned char* __restrict__ pcnt) {
    const int i = blockIdx.x, c = threadIdx.x;
    const uint4* lst = (const uint4*)(nbr + c * MAXD);
    const unsigned lim = (unsigned)(i * 64);
    int p = 0;
    #pragma unroll
    for (int b = 0; b < MAXD / 4; ++b) {
        uint4 q = lst[b];
        p += (q.x < lim) + (q.y < lim) + (q.z < lim) + (q.w < lim);
    }
    pcnt[i * NN + c] = (unsigned char)p;
    degt[i * NN + c] = __float2bfloat16(rsqrtf((float)(p > 0 ? p : 1)));
}

// base = z[512,256] @ W1[0:256, 0:64].
__global__ __launch_bounds__(256) void gemm_base(const float* __restrict__ z,
                                                 const float* __restrict__ W1,
                                                 float* __restrict__ base) {
    __shared__ float As[16][68];
    __shared__ float Bsh[16][68];
    const int bi = blockIdx.x;
    const int tid = threadIdx.x, tx = tid & 15, ty = tid >> 4;
    float acc[4][4] = {};
    for (int kk = 0; kk < 256; kk += 16) {
        #pragma unroll
        for (int l = 0; l < 4; ++l) {
            int id = tid + (l << 8);
            int m = id >> 4, k = id & 15;
            As[k][m] = z[(bi * 64 + m) * 256 + kk + k];
        }
        #pragma unroll
        for (int l = 0; l < 4; ++l) {
            int id = tid + (l << 8);
            int k = id >> 6, n2 = id & 63;
            Bsh[k][n2] = W1[(kk + k) * 64 + n2];
        }
        __syncthreads();
        #pragma unroll
        for (int k = 0; k < 16; ++k) {
            float4 a = *(const float4*)&As[k][ty * 4];
            float4 b = *(const float4*)&Bsh[k][tx * 4];
            float ar[4] = {a.x, a.y, a.z, a.w};
            float br[4] = {b.x, b.y, b.z, b.w};
            #pragma unroll
            for (int p = 0; p < 4; ++p)
                #pragma unroll
                for (int q = 0; q < 4; ++q)
                    acc[p][q] = fmaf(ar[p], br[q], acc[p][q]);
        }
        __syncthreads();
    }
    #pragma unroll
    for (int p = 0; p < 4; ++p) {
        float4 st = make_float4(acc[p][0], acc[p][1], acc[p][2], acc[p][3]);
        *(float4*)&base[(bi * 64 + ty * 4 + p) * NH + tx * 4] = st;
    }
}

// out = z @ z^T (fully overwrites d_out; supp accumulates on top afterwards).
__global__ __launch_bounds__(256) void gemm_x(const float* __restrict__ z,
                                              float* __restrict__ out) {
    __shared__ float As[16][68];
    __shared__ float Bsh[16][68];
    const int bi = blockIdx.y, bj = blockIdx.x;
    const int tid = threadIdx.x, tx = tid & 15, ty = tid >> 4;
    float acc[4][4] = {};
    for (int kk = 0; kk < 256; kk += 16) {
        #pragma unroll
        for (int l = 0; l < 4; ++l) {
            int id = tid + (l << 8);
            int m = id >> 4, k = id & 15;
            As[k][m]  = z[(bi * 64 + m) * 256 + kk + k];
            Bsh[k][m] = z[(bj * 64 + m) * 256 + kk + k];
        }
        __syncthreads();
        #pragma unroll
        for (int k = 0; k < 16; ++k) {
            float4 a = *(const float4*)&As[k][ty * 4];
            float4 b = *(const float4*)&Bsh[k][tx * 4];
            float ar[4] = {a.x, a.y, a.z, a.w};
            float br[4] = {b.x, b.y, b.z, b.w};
            #pragma unroll
            for (int p = 0; p < 4; ++p)
                #pragma unroll
                for (int q = 0; q < 4; ++q)
                    acc[p][q] = fmaf(ar[p], br[q], acc[p][q]);
        }
        __syncthreads();
    }
    #pragma unroll
    for (int p = 0; p < 4; ++p) {
        float4 st = make_float4(acc[p][0], acc[p][1], acc[p][2], acc[p][3]);
        *(float4*)&out[(bi * 64 + ty * 4 + p) * NN + bj * 64 + tx * 4] = st;
    }
}

// One block per i (desc). Stage g2[l][h] = deg_i[l]*base[l][h] fp16 (rows >= i
// zeroed once). hid row i computed in LDS; supplement fused: out[i][j] += s,
// out[j][i] += s with s = 0.5*deg[j]*sum_{k in nbr(j), k<i} deg[k]*hid[k].
// Over-reads past pcnt hit zero rows (real l>=i, or sentinel row 511): free pad.
__global__ __launch_bounds__(512) void hid_fused(const unsigned* __restrict__ nbr,
                                                 const unsigned char* __restrict__ pcnt,
                                                 const float* __restrict__ base,
                                                 const __hip_bfloat16* __restrict__ degt,
                                                 const float* __restrict__ W2,
                                                 float* __restrict__ out) {
    __shared__ _Float16 g2[NN * NH];   // 64 KB, deg-scaled base
    __shared__ float degl[NN];
    __shared__ float phl[NN];          // hid, then deg*hid
    const int i = 511 - (int)blockIdx.x;   // big i dispatched first
    const int tid = threadIdx.x, lane = tid & 63, w = tid >> 6;

    degl[tid] = __bfloat162float(degt[i * NN + tid]);
    unsigned* g2u = (unsigned*)g2;
    for (int t = tid; t < (NN - i) * 32; t += 512) g2u[i * 32 + t] = 0u;
    __syncthreads();
    for (int t = tid; t < i * 64; t += 512) {
        int l = t >> 6;
        g2[t] = (_Float16)(degl[l] * base[t]);
    }
    __syncthreads();

    const float w2 = W2[lane];
    for (int k = w; k < i; k += 8) {
        const int ks = __builtin_amdgcn_readfirstlane(k);
        const int pk = pcnt[i * NN + ks];
        const uint4* l4 = (const uint4*)(nbr + ks * MAXD);
        const int nb = (pk + 3) >> 2;
        float a0 = 0.f, a1 = 0.f, a2 = 0.f, a3 = 0.f;
        for (int b = 0; b < nb; ++b) {
            uint4 q = l4[b];
            a0 += (float)g2[q.x + lane];
            a1 += (float)g2[q.y + lane];
            a2 += (float)g2[q.z + lane];
            a3 += (float)g2[q.w + lane];
        }
        float val = fmaxf(degl[ks] * ((a0 + a1) + (a2 + a3)), 0.f) * w2;
        #pragma unroll
        for (int off = 32; off; off >>= 1) val += __shfl_xor(val, off, 64);
        if (lane == 0) phl[ks] = val;
    }
    __syncthreads();
    phl[tid] = (tid < i) ? degl[tid] * phl[tid] : 0.0f;
    __syncthreads();

    if (tid < i) {
        const int p = pcnt[i * NN + tid];
        const uint4* l4 = (const uint4*)(nbr + tid * MAXD);
        const int nb = (p + 3) >> 2;
        float s = 0.f;
        for (int b = 0; b < nb; ++b) {
            uint4 q = l4[b];   // over-read entries land on phl[r>=i] == 0
            s += phl[q.x >> 6] + phl[q.y >> 6] + phl[q.z >> 6] + phl[q.w >> 6];
        }
        s *= 0.5f * degl[tid];
        out[i * NN + tid] += s;
        out[tid * NN + i] += s;
    }
}

extern "C" void kernel_launch(void* const* d_in, const int* in_sizes, int n_in,
                              void* d_out, int out_size, void* d_ws, size_t ws_size,
                              hipStream_t stream) {
    const float* z   = (const float*)d_in[0];
    const float* adj = (const float*)d_in[1];
    const float* W1  = (const float*)d_in[2];
    const float* W2  = (const float*)d_in[3];
    float* out = (float*)d_out;

    char* wsp = (char*)d_ws;
    unsigned*       nbr  = (unsigned*)      (wsp + 0);
    float*          base = (float*)         (wsp + 163840);
    __hip_bfloat16* degt = (__hip_bfloat16*)(wsp + 294912);
    unsigned char*  pcnt = (unsigned char*) (wsp + 819200);

    build_lists<<<NN, 512, 0, stream>>>(adj, nbr);
    build_deg<<<NN, NN, 0, stream>>>(nbr, degt, pcnt);
    gemm_base<<<8, 256, 0, stream>>>(z, W1, base);
    gemm_x<<<dim3(8, 8), 256, 0, stream>>>(z, out);
    hid_fused<<<NN, 512, 0, stream>>>(nbr, pcnt, base, degt, W2, out);
}

// Round 4
// 107.372 us; speedup vs baseline: 2.3686x; 1.0870x over previous
//
#include <hip/hip_runtime.h>
#include <hip/hip_bf16.h>

#define NN 512
#define NH 64
#define MAXD 80            // binomial(511,1/16): mean 32, sigma 5.5 -> +8.7 sigma
#define ZBYTE (511 * 128)  // sentinel -> byte offset of row 511 of g2 (kept zero)

typedef _Float16 h4 __attribute__((ext_vector_type(4)));

// ---------------- ws layout (bytes) ----------------
// nbr   : NN*MAXD*4 = 163840 @ 0        entries = r*128 (byte row offset), sentinel ZBYTE
// base  : NN*NH*4   = 131072 @ 163840   z @ W1[:256]
// pcntT : NN*NN*1   = 262144 @ 294912   u8 pcntT[c][i] = #{r in nbr(c): r < i}
// total = 557056

// adj symmetric => column c nonzeros == row c nonzeros. One coalesced row read;
// ballot prefix gives BOTH the order-preserving compaction position AND the
// exclusive prefix count pcnt[i][c] (stored transposed for coalesced writes).
__global__ __launch_bounds__(512) void build_all(const float* __restrict__ adj,
                                                 unsigned* __restrict__ nbr,
                                                 unsigned char* __restrict__ pcntT) {
    const int c = blockIdx.x;
    const int t = threadIdx.x;
    const int lane = t & 63, w = t >> 6;
    __shared__ int wcnt[8];
    bool f = (adj[c * NN + t] != 0.0f);
    unsigned long long m = __ballot(f);
    int before = __popcll(m & ((1ull << lane) - 1ull));
    if (lane == 0) wcnt[w] = __popcll(m);
    __syncthreads();
    int pre = 0, total = 0;
    #pragma unroll
    for (int j = 0; j < 8; ++j) {
        int x = wcnt[j];
        pre += (j < w) ? x : 0;
        total += x;
    }
    pcntT[c * NN + t] = (unsigned char)(pre + before);  // #neighbors of c strictly < t
    unsigned* row = nbr + c * MAXD;
    int pos = pre + before;
    if (f && pos < MAXD) row[pos] = (unsigned)(t << 7);
    int m2 = total < MAXD ? total : MAXD;
    for (int j = m2 + t; j < MAXD; j += 512) row[j] = ZBYTE;
}

// base = z[512,256] @ W1[0:256, 0:64].
__global__ __launch_bounds__(256) void gemm_base(const float* __restrict__ z,
                                                 const float* __restrict__ W1,
                                                 float* __restrict__ base) {
    __shared__ float As[16][68];
    __shared__ float Bsh[16][68];
    const int bi = blockIdx.x;
    const int tid = threadIdx.x, tx = tid & 15, ty = tid >> 4;
    float acc[4][4] = {};
    for (int kk = 0; kk < 256; kk += 16) {
        #pragma unroll
        for (int l = 0; l < 4; ++l) {
            int id = tid + (l << 8);
            int m = id >> 4, k = id & 15;
            As[k][m] = z[(bi * 64 + m) * 256 + kk + k];
        }
        #pragma unroll
        for (int l = 0; l < 4; ++l) {
            int id = tid + (l << 8);
            int k = id >> 6, n2 = id & 63;
            Bsh[k][n2] = W1[(kk + k) * 64 + n2];
        }
        __syncthreads();
        #pragma unroll
        for (int k = 0; k < 16; ++k) {
            float4 a = *(const float4*)&As[k][ty * 4];
            float4 b = *(const float4*)&Bsh[k][tx * 4];
            float ar[4] = {a.x, a.y, a.z, a.w};
            float br[4] = {b.x, b.y, b.z, b.w};
            #pragma unroll
            for (int p = 0; p < 4; ++p)
                #pragma unroll
                for (int q = 0; q < 4; ++q)
                    acc[p][q] = fmaf(ar[p], br[q], acc[p][q]);
        }
        __syncthreads();
    }
    #pragma unroll
    for (int p = 0; p < 4; ++p) {
        float4 st = make_float4(acc[p][0], acc[p][1], acc[p][2], acc[p][3]);
        *(float4*)&base[(bi * 64 + ty * 4 + p) * NH + tx * 4] = st;
    }
}

// out = z @ z^T (overwrites d_out; hid_fused accumulates on top afterwards).
__global__ __launch_bounds__(256) void gemm_x(const float* __restrict__ z,
                                              float* __restrict__ out) {
    __shared__ float As[16][68];
    __shared__ float Bsh[16][68];
    const int bi = blockIdx.y, bj = blockIdx.x;
    const int tid = threadIdx.x, tx = tid & 15, ty = tid >> 4;
    float acc[4][4] = {};
    for (int kk = 0; kk < 256; kk += 16) {
        #pragma unroll
        for (int l = 0; l < 4; ++l) {
            int id = tid + (l << 8);
            int m = id >> 4, k = id & 15;
            As[k][m]  = z[(bi * 64 + m) * 256 + kk + k];
            Bsh[k][m] = z[(bj * 64 + m) * 256 + kk + k];
        }
        __syncthreads();
        #pragma unroll
        for (int k = 0; k < 16; ++k) {
            float4 a = *(const float4*)&As[k][ty * 4];
            float4 b = *(const float4*)&Bsh[k][tx * 4];
            float ar[4] = {a.x, a.y, a.z, a.w};
            float br[4] = {b.x, b.y, b.z, b.w};
            #pragma unroll
            for (int p = 0; p < 4; ++p)
                #pragma unroll
                for (int q = 0; q < 4; ++q)
                    acc[p][q] = fmaf(ar[p], br[q], acc[p][q]);
        }
        __syncthreads();
    }
    #pragma unroll
    for (int p = 0; p < 4; ++p) {
        float4 st = make_float4(acc[p][0], acc[p][1], acc[p][2], acc[p][3]);
        *(float4*)&out[(bi * 64 + ty * 4 + p) * NN + bj * 64 + tx * 4] = st;
    }
}

// One block per i (desc). g2[l][h] = deg_i[l]*base[l][h] fp16, rows >= i zeroed.
// k-loop: quarter-wave-per-neighbor ds_read_b64 (512B/instr, bank-balanced),
// packed f16 accumulate. Fused supplement: out[i][j] += s, out[j][i] += s.
__global__ __launch_bounds__(512) void hid_fused(const unsigned* __restrict__ nbr,
                                                 const unsigned char* __restrict__ pcntT,
                                                 const float* __restrict__ base,
                                                 const float* __restrict__ W2,
                                                 float* __restrict__ out) {
    __shared__ _Float16 g2[NN * NH];   // 64 KB
    __shared__ float degl[NN];
    __shared__ float phl[NN];
    __shared__ int   pcl[NN];
    const int i = 511 - (int)blockIdx.x;   // big i dispatched first
    const int tid = threadIdx.x, lane = tid & 63, w = tid >> 6;

    int pc = pcntT[tid * NN + i];          // strided u8 (L2), once per block
    pcl[tid]  = pc;
    degl[tid] = rsqrtf((float)(pc > 0 ? pc : 1));
    unsigned* g2u = (unsigned*)g2;
    for (int t = tid; t < (NN - i) * 32; t += 512) g2u[i * 32 + t] = 0u;
    __syncthreads();
    for (int t = tid; t < i * 16; t += 512) {
        int l = t >> 4, h0 = (t & 15) << 2;
        const float4 b4 = *(const float4*)&base[l * 64 + h0];
        float d = degl[l];
        h4 v = {(_Float16)(d * b4.x), (_Float16)(d * b4.y),
                (_Float16)(d * b4.z), (_Float16)(d * b4.w)};
        *(h4*)&g2[l * 64 + h0] = v;
    }
    __syncthreads();

    const bool s0 = (lane & 16) != 0, s1 = (lane & 32) != 0;
    const int  lofs = (lane & 15) << 3;              // byte offset within 128B row
    const float4 w2v = *(const float4*)&W2[(lane & 15) << 2];
    const char* g2b = (const char*)g2;

    for (int k = w; k < i; k += 8) {
        const int ks = __builtin_amdgcn_readfirstlane(k);
        const int pk = pcl[ks];
        const uint4* l4 = (const uint4*)(nbr + ks * MAXD);
        const int nb = (pk + 3) >> 2;
        h4 acc = {};
        for (int b = 0; b < nb; ++b) {
            uint4 q = l4[b];                          // uniform -> s_load
            unsigned r01 = s0 ? q.y : q.x;
            unsigned r23 = s0 ? q.w : q.z;
            unsigned rs  = s1 ? r23 : r01;            // quarter-selected row base
            acc += *(const h4*)(g2b + (rs + lofs));   // over-reads hit zero rows
        }
        // merge the 4 quarters (packed), then all lanes hold same 4 h-sums
        #pragma unroll
        for (int mm = 16; mm <= 32; mm <<= 1) {
            union { h4 h; int v[2]; } u, r;
            u.h = acc;
            r.v[0] = __shfl_xor(u.v[0], mm, 64);
            r.v[1] = __shfl_xor(u.v[1], mm, 64);
            acc += r.h;
        }
        float dk = degl[ks];
        float val = fmaxf(dk * (float)acc[0], 0.f) * w2v.x
                  + fmaxf(dk * (float)acc[1], 0.f) * w2v.y
                  + fmaxf(dk * (float)acc[2], 0.f) * w2v.z
                  + fmaxf(dk * (float)acc[3], 0.f) * w2v.w;
        #pragma unroll
        for (int mm = 1; mm <= 8; mm <<= 1) val += __shfl_xor(val, mm, 64);
        if (lane == 0) phl[ks] = val;
    }
    __syncthreads();
    phl[tid] = (tid < i) ? degl[tid] * phl[tid] : 0.0f;
    __syncthreads();

    if (tid < i) {
        const int p = pcl[tid];
        const uint4* l4 = (const uint4*)(nbr + tid * MAXD);
        const int nb = (p + 3) >> 2;
        float s = 0.f;
        for (int b = 0; b < nb; ++b) {
            uint4 q = l4[b];   // over-read entries land on phl[r>=i] == 0
            s += phl[q.x >> 7] + phl[q.y >> 7] + phl[q.z >> 7] + phl[q.w >> 7];
        }
        s *= 0.5f * degl[tid];
        out[i * NN + tid] += s;
        out[tid * NN + i] += s;
    }
}

extern "C" void kernel_launch(void* const* d_in, const int* in_sizes, int n_in,
                              void* d_out, int out_size, void* d_ws, size_t ws_size,
                              hipStream_t stream) {
    const float* z   = (const float*)d_in[0];
    const float* adj = (const float*)d_in[1];
    const float* W1  = (const float*)d_in[2];
    const float* W2  = (const float*)d_in[3];
    float* out = (float*)d_out;

    char* wsp = (char*)d_ws;
    unsigned*       nbr   = (unsigned*)      (wsp + 0);
    float*          base  = (float*)         (wsp + 163840);
    unsigned char*  pcntT = (unsigned char*) (wsp + 294912);

    build_all<<<NN, 512, 0, stream>>>(adj, nbr, pcntT);
    gemm_base<<<8, 256, 0, stream>>>(z, W1, base);
    gemm_x<<<dim3(8, 8), 256, 0, stream>>>(z, out);
    hid_fused<<<NN, 512, 0, stream>>>(nbr, pcntT, base, W2, out);
}

// Round 5
// 60.443 us; speedup vs baseline: 4.2077x; 1.7764x over previous
//
#include <hip/hip_runtime.h>
#include <hip/hip_bf16.h>

#define NN 512
#define NH 64
#define MAXD 96            // list capacity (deg mean 32, sigma 5.5)
#define ZBYTE (511 * 128)  // sentinel -> byte offset of row 511 (deg=0 always)

typedef _Float16 h4 __attribute__((ext_vector_type(4)));

// ---------------- ws layout (bytes) ----------------
// nbr   : NN*MAXD*4 = 196608 @ 0        entries = r*128 (byte row offset), sentinel ZBYTE
// base  : NN*NH*4   = 131072 @ 196608   z @ W1[:256]
// pcntT : NN*NN*1   = 262144 @ 327680   u8 pcntT[c][i] = #{r in nbr(c): r < i}
// total = 589824

// adj symmetric => column c nonzeros == row c nonzeros. One coalesced row read;
// ballot prefix gives BOTH the compaction position AND pcnt (stored transposed).
__global__ __launch_bounds__(512) void build_all(const float* __restrict__ adj,
                                                 unsigned* __restrict__ nbr,
                                                 unsigned char* __restrict__ pcntT) {
    const int c = blockIdx.x;
    const int t = threadIdx.x;
    const int lane = t & 63, w = t >> 6;
    __shared__ int wcnt[8];
    bool f = (adj[c * NN + t] != 0.0f);
    unsigned long long m = __ballot(f);
    int before = __popcll(m & ((1ull << lane) - 1ull));
    if (lane == 0) wcnt[w] = __popcll(m);
    __syncthreads();
    int pre = 0, total = 0;
    #pragma unroll
    for (int j = 0; j < 8; ++j) {
        int x = wcnt[j];
        pre += (j < w) ? x : 0;
        total += x;
    }
    pcntT[c * NN + t] = (unsigned char)(pre + before);
    unsigned* row = nbr + c * MAXD;
    int pos = pre + before;
    if (f && pos < MAXD) row[pos] = (unsigned)(t << 7);
    int m2 = total < MAXD ? total : MAXD;
    for (int j = m2 + t; j < MAXD; j += 512) row[j] = ZBYTE;
}

// base = z[512,256] @ W1[0:256,0:64]. 16 blocks x 32 rows, micro 2x4.
__global__ __launch_bounds__(256) void gemm_base(const float* __restrict__ z,
                                                 const float* __restrict__ W1,
                                                 float* __restrict__ base) {
    __shared__ float As[16][34];
    __shared__ float Bsh[16][68];
    const int bi = blockIdx.x;
    const int tid = threadIdx.x, tx = tid & 15, ty = tid >> 4;
    float acc[2][4] = {};
    for (int kk = 0; kk < 256; kk += 16) {
        #pragma unroll
        for (int l = 0; l < 2; ++l) {
            int id = tid + (l << 8);
            int m = id >> 4, k = id & 15;
            As[k][m] = z[(bi * 32 + m) * 256 + kk + k];
        }
        #pragma unroll
        for (int l = 0; l < 4; ++l) {
            int id = tid + (l << 8);
            int k = id >> 6, n2 = id & 63;
            Bsh[k][n2] = W1[(kk + k) * 64 + n2];
        }
        __syncthreads();
        #pragma unroll
        for (int k = 0; k < 16; ++k) {
            float2 a = *(const float2*)&As[k][ty * 2];
            float4 b = *(const float4*)&Bsh[k][tx * 4];
            float ar[2] = {a.x, a.y};
            float br[4] = {b.x, b.y, b.z, b.w};
            #pragma unroll
            for (int p = 0; p < 2; ++p)
                #pragma unroll
                for (int q = 0; q < 4; ++q)
                    acc[p][q] = fmaf(ar[p], br[q], acc[p][q]);
        }
        __syncthreads();
    }
    #pragma unroll
    for (int p = 0; p < 2; ++p) {
        float4 st = make_float4(acc[p][0], acc[p][1], acc[p][2], acc[p][3]);
        *(float4*)&base[(bi * 32 + ty * 2 + p) * NH + tx * 4] = st;
    }
}

// out = z @ z^T. 256 blocks of 32x32 tiles, micro 2x2.
__global__ __launch_bounds__(256) void gemm_x(const float* __restrict__ z,
                                              float* __restrict__ out) {
    __shared__ float As[32][34];
    __shared__ float Bs[32][34];
    const int bi = blockIdx.y, bj = blockIdx.x;
    const int tid = threadIdx.x, tx = tid & 15, ty = tid >> 4;
    float acc[2][2] = {};
    for (int kk = 0; kk < 256; kk += 32) {
        #pragma unroll
        for (int l = 0; l < 4; ++l) {
            int id = tid + (l << 8);
            int m = id >> 5, k = id & 31;
            As[k][m] = z[(bi * 32 + m) * 256 + kk + k];
            Bs[k][m] = z[(bj * 32 + m) * 256 + kk + k];
        }
        __syncthreads();
        #pragma unroll
        for (int k = 0; k < 32; ++k) {
            float2 a = *(const float2*)&As[k][ty * 2];
            float2 b = *(const float2*)&Bs[k][tx * 2];
            acc[0][0] = fmaf(a.x, b.x, acc[0][0]);
            acc[0][1] = fmaf(a.x, b.y, acc[0][1]);
            acc[1][0] = fmaf(a.y, b.x, acc[1][0]);
            acc[1][1] = fmaf(a.y, b.y, acc[1][1]);
        }
        __syncthreads();
    }
    #pragma unroll
    for (int p = 0; p < 2; ++p) {
        float2 st = make_float2(acc[p][0], acc[p][1]);
        *(float2*)&out[(bi * 32 + ty * 2 + p) * NN + bj * 32 + tx * 2] = st;
    }
}

// One block per i (desc, 1024 thr). g2 = raw base fp16 (i-independent).
// deghl[r] = packed half2 deg_i[r], 0 for r >= i  -> masking & sentinels free.
// Quarter q of each wave owns one k: 16 lanes read the 128B row per neighbor,
// fma by broadcast deg; 4 independent k-chains per wave hide latency.
__global__ __launch_bounds__(1024, 8) void hid_fused(const unsigned* __restrict__ nbr,
                                                     const unsigned char* __restrict__ pcntT,
                                                     const float* __restrict__ base,
                                                     const float* __restrict__ W2,
                                                     float* __restrict__ out) {
    __shared__ _Float16 g2[NN * NH];   // 64 KB raw base
    __shared__ unsigned deghl[NN];     // packed half2 deg
    __shared__ float degl[NN];
    __shared__ float phl[NN];
    __shared__ int   pcl[NN];
    const int i = 511 - (int)blockIdx.x;
    if (i < 1) return;
    const int tid = threadIdx.x, lane = tid & 63, w = tid >> 6;

    if (tid < NN) {
        int pc = (int)pcntT[tid * NN + i];
        pc = pc < MAXD ? pc : MAXD;
        pcl[tid] = pc;
        float d = (tid < i) ? rsqrtf((float)(pc > 0 ? pc : 1)) : 0.0f;
        degl[tid] = d;
        union { _Float16 h[2]; unsigned u; } du;
        du.h[0] = (_Float16)d; du.h[1] = (_Float16)d;
        deghl[tid] = du.u;
    }
    for (int t = tid; t < NN * 16; t += 1024) {
        int l = t >> 4, h0 = (t & 15) << 2;
        const float4 b4 = *(const float4*)&base[l * 64 + h0];
        h4 v = {(_Float16)b4.x, (_Float16)b4.y, (_Float16)b4.z, (_Float16)b4.w};
        *(h4*)&g2[l * 64 + h0] = v;
    }
    __syncthreads();

    const int q = lane >> 4;                 // quarter 0..3
    const int lofs = (lane & 15) << 3;       // byte offset within 128B row
    const float4 w2v = *(const float4*)&W2[(lane & 15) << 2];
    const char* g2b = (const char*)g2;

    for (int k4 = w * 4; k4 < i; k4 += 64) {
        const int kq = k4 + q;
        const int kqc = kq < 511 ? kq : 511;
        int pk = (kq < i) ? pcl[kqc] : 0;
        int mx = pk;
        mx = max(mx, __shfl_xor(mx, 16, 64));
        mx = max(mx, __shfl_xor(mx, 32, 64));
        const int nbu = __builtin_amdgcn_readfirstlane((mx + 3) >> 2);
        const char* lb = (const char*)(nbr + kqc * MAXD);
        h4 acc = {};
        int off = 0;
        for (int g = 0; g < nbu; ++g) {
            unsigned rs0 = *(const unsigned*)(lb + off);
            unsigned rs1 = *(const unsigned*)(lb + off + 4);
            unsigned rs2 = *(const unsigned*)(lb + off + 8);
            unsigned rs3 = *(const unsigned*)(lb + off + 12);
            off += 16;
            union { unsigned u[2]; h4 h; } d0, d1, d2, d3;
            d0.u[0] = deghl[rs0 >> 7]; d0.u[1] = d0.u[0];
            d1.u[0] = deghl[rs1 >> 7]; d1.u[1] = d1.u[0];
            d2.u[0] = deghl[rs2 >> 7]; d2.u[1] = d2.u[0];
            d3.u[0] = deghl[rs3 >> 7]; d3.u[1] = d3.u[0];
            acc += *(const h4*)(g2b + rs0 + lofs) * d0.h;
            acc += *(const h4*)(g2b + rs1 + lofs) * d1.h;
            acc += *(const h4*)(g2b + rs2 + lofs) * d2.h;
            acc += *(const h4*)(g2b + rs3 + lofs) * d3.h;
        }
        const float dk = degl[kqc];          // 0 for kq >= i
        float val = fmaxf(dk * (float)acc[0], 0.f) * w2v.x
                  + fmaxf(dk * (float)acc[1], 0.f) * w2v.y
                  + fmaxf(dk * (float)acc[2], 0.f) * w2v.z
                  + fmaxf(dk * (float)acc[3], 0.f) * w2v.w;
        #pragma unroll
        for (int mm = 1; mm <= 8; mm <<= 1) val += __shfl_xor(val, mm, 64);
        if ((lane & 15) == 0 && kq < i) phl[kq] = val;
    }
    __syncthreads();
    if (tid < NN) phl[tid] = (tid < i) ? degl[tid] * phl[tid] : 0.0f;
    __syncthreads();

    if (tid < i) {
        const int p = pcl[tid];
        const uint4* l4 = (const uint4*)(nbr + tid * MAXD);
        const int nb = (p + 3) >> 2;
        float s = 0.f;
        for (int b = 0; b < nb; ++b) {
            uint4 qv = l4[b];  // over-read entries land on phl[r>=i] == 0
            s += phl[qv.x >> 7] + phl[qv.y >> 7] + phl[qv.z >> 7] + phl[qv.w >> 7];
        }
        s *= 0.5f * degl[tid];
        out[i * NN + tid] += s;
        out[tid * NN + i] += s;
    }
}

extern "C" void kernel_launch(void* const* d_in, const int* in_sizes, int n_in,
                              void* d_out, int out_size, void* d_ws, size_t ws_size,
                              hipStream_t stream) {
    const float* z   = (const float*)d_in[0];
    const float* adj = (const float*)d_in[1];
    const float* W1  = (const float*)d_in[2];
    const float* W2  = (const float*)d_in[3];
    float* out = (float*)d_out;

    char* wsp = (char*)d_ws;
    unsigned*       nbr   = (unsigned*)      (wsp + 0);
    float*          base  = (float*)         (wsp + 196608);
    unsigned char*  pcntT = (unsigned char*) (wsp + 327680);

    build_all<<<NN, 512, 0, stream>>>(adj, nbr, pcntT);
    gemm_base<<<16, 256, 0, stream>>>(z, W1, base);
    gemm_x<<<dim3(16, 16), 256, 0, stream>>>(z, out);
    hid_fused<<<NN, 1024, 0, stream>>>(nbr, pcntT, base, W2, out);
}

// Round 6
// 59.957 us; speedup vs baseline: 4.2418x; 1.0081x over previous
//
#include <hip/hip_runtime.h>
#include <hip/hip_bf16.h>

#define NN 512
#define NH 64
#define MAXD 96            // list capacity (deg mean 32, sigma 5.5)
#define ZBYTE (511 * 128)  // sentinel -> byte offset of row 511 (deg=0 always)
#define KC 256             // k-chunk per hidk block

typedef _Float16 h4 __attribute__((ext_vector_type(4)));

// ---------------- ws layout (bytes) ----------------
// nbr   : NN*MAXD*4 = 196608 @ 0        entries = r*128 (byte row offset), sentinel ZBYTE
// g16   : NN*NH*2   = 65536  @ 196608   fp16 z@W1 tile (written by gemm_base)
// pcntT : NN*NN*1   = 262144 @ 262144   u8 pcntT[c][i] = #{r in nbr(c): r < i}
// hidt  : NN*NN*4   = 1048576@ 524288   f32 hid[i][k] (valid k<i only)
// total = 1572864

// adj symmetric => column c nonzeros == row c nonzeros. One coalesced row read;
// ballot prefix gives BOTH the compaction position AND pcnt (stored transposed).
__global__ __launch_bounds__(512) void build_all(const float* __restrict__ adj,
                                                 unsigned* __restrict__ nbr,
                                                 unsigned char* __restrict__ pcntT) {
    const int c = blockIdx.x;
    const int t = threadIdx.x;
    const int lane = t & 63, w = t >> 6;
    __shared__ int wcnt[8];
    bool f = (adj[c * NN + t] != 0.0f);
    unsigned long long m = __ballot(f);
    int before = __popcll(m & ((1ull << lane) - 1ull));
    if (lane == 0) wcnt[w] = __popcll(m);
    __syncthreads();
    int pre = 0, total = 0;
    #pragma unroll
    for (int j = 0; j < 8; ++j) {
        int x = wcnt[j];
        pre += (j < w) ? x : 0;
        total += x;
    }
    pcntT[c * NN + t] = (unsigned char)(pre + before);
    unsigned* row = nbr + c * MAXD;
    int pos = pre + before;
    if (f && pos < MAXD) row[pos] = (unsigned)(t << 7);
    int m2 = total < MAXD ? total : MAXD;
    for (int j = m2 + t; j < MAXD; j += 512) row[j] = ZBYTE;
}

// g16 = fp16( z[512,256] @ W1[0:256,0:64] ). 16 blocks x 32 rows, micro 2x4.
__global__ __launch_bounds__(256) void gemm_base(const float* __restrict__ z,
                                                 const float* __restrict__ W1,
                                                 _Float16* __restrict__ g16) {
    __shared__ float As[16][34];
    __shared__ float Bsh[16][68];
    const int bi = blockIdx.x;
    const int tid = threadIdx.x, tx = tid & 15, ty = tid >> 4;
    float acc[2][4] = {};
    for (int kk = 0; kk < 256; kk += 16) {
        #pragma unroll
        for (int l = 0; l < 2; ++l) {
            int id = tid + (l << 8);
            int m = id >> 4, k = id & 15;
            As[k][m] = z[(bi * 32 + m) * 256 + kk + k];
        }
        #pragma unroll
        for (int l = 0; l < 4; ++l) {
            int id = tid + (l << 8);
            int k = id >> 6, n2 = id & 63;
            Bsh[k][n2] = W1[(kk + k) * 64 + n2];
        }
        __syncthreads();
        #pragma unroll
        for (int k = 0; k < 16; ++k) {
            float2 a = *(const float2*)&As[k][ty * 2];
            float4 b = *(const float4*)&Bsh[k][tx * 4];
            float ar[2] = {a.x, a.y};
            float br[4] = {b.x, b.y, b.z, b.w};
            #pragma unroll
            for (int p = 0; p < 2; ++p)
                #pragma unroll
                for (int q = 0; q < 4; ++q)
                    acc[p][q] = fmaf(ar[p], br[q], acc[p][q]);
        }
        __syncthreads();
    }
    #pragma unroll
    for (int p = 0; p < 2; ++p) {
        h4 v = {(_Float16)acc[p][0], (_Float16)acc[p][1],
                (_Float16)acc[p][2], (_Float16)acc[p][3]};
        *(h4*)&g16[(bi * 32 + ty * 2 + p) * NH + tx * 4] = v;
    }
}

// out = z @ z^T. 256 blocks of 32x32 tiles, micro 2x2.
__global__ __launch_bounds__(256) void gemm_x(const float* __restrict__ z,
                                              float* __restrict__ out) {
    __shared__ float As[32][34];
    __shared__ float Bs[32][34];
    const int bi = blockIdx.y, bj = blockIdx.x;
    const int tid = threadIdx.x, tx = tid & 15, ty = tid >> 4;
    float acc[2][2] = {};
    for (int kk = 0; kk < 256; kk += 32) {
        #pragma unroll
        for (int l = 0; l < 4; ++l) {
            int id = tid + (l << 8);
            int m = id >> 5, k = id & 31;
            As[k][m] = z[(bi * 32 + m) * 256 + kk + k];
            Bs[k][m] = z[(bj * 32 + m) * 256 + kk + k];
        }
        __syncthreads();
        #pragma unroll
        for (int k = 0; k < 32; ++k) {
            float2 a = *(const float2*)&As[k][ty * 2];
            float2 b = *(const float2*)&Bs[k][tx * 2];
            acc[0][0] = fmaf(a.x, b.x, acc[0][0]);
            acc[0][1] = fmaf(a.x, b.y, acc[0][1]);
            acc[1][0] = fmaf(a.y, b.x, acc[1][0]);
            acc[1][1] = fmaf(a.y, b.y, acc[1][1]);
        }
        __syncthreads();
    }
    #pragma unroll
    for (int p = 0; p < 2; ++p) {
        float2 st = make_float2(acc[p][0], acc[p][1]);
        *(float2*)&out[(bi * 32 + ty * 2 + p) * NN + bj * 32 + tx * 2] = st;
    }
}

// Balanced hid: one block per (i, KC-chunk of k). g2 = raw fp16 tile (copied
// from g16, i-independent). deghl[r] packed-half2 deg_i[r], 0 for r>=i ->
// masking & sentinels free. Quarter q of each wave owns one k; 16 lanes read
// the 128B row per neighbor; 4 independent k-chains per wave hide latency.
__global__ __launch_bounds__(1024, 8) void hidk(const unsigned* __restrict__ nbr,
                                                const unsigned char* __restrict__ pcntT,
                                                const _Float16* __restrict__ g16,
                                                const float* __restrict__ W2,
                                                float* __restrict__ hidt) {
    __shared__ _Float16 g2[NN * NH];   // 64 KB
    __shared__ unsigned deghl[NN];
    __shared__ float degl[NN];
    __shared__ short pcl[KC];
    const int i  = 511 - (int)blockIdx.y;   // big i first
    const int cb = (int)blockIdx.x * KC;
    if (cb >= i) return;
    const int kend = (cb + KC < i) ? cb + KC : i;
    const int tid = threadIdx.x, lane = tid & 63, w = tid >> 6;

    if (tid < NN) {
        int pc = (int)pcntT[tid * NN + i];
        float d = (tid < i) ? rsqrtf((float)(pc > 0 ? pc : 1)) : 0.0f;
        degl[tid] = d;
        union { _Float16 h[2]; unsigned u; } du;
        du.h[0] = (_Float16)d; du.h[1] = (_Float16)d;
        deghl[tid] = du.u;
    }
    if (tid < KC) pcl[tid] = (short)pcntT[(cb + tid) * NN + i];
    {
        const uint4* src = (const uint4*)g16;
        uint4* dst = (uint4*)g2;
        #pragma unroll
        for (int t = 0; t < 4; ++t) dst[tid + (t << 10)] = src[tid + (t << 10)];
    }
    __syncthreads();

    const int q = lane >> 4;
    const int lofs = (lane & 15) << 3;
    const float4 w2v = *(const float4*)&W2[(lane & 15) << 2];
    const char* g2b = (const char*)g2;

    for (int k0 = cb + w * 4; k0 < kend; k0 += 64) {
        const int kq = k0 + q;
        int pk = (kq < kend) ? (int)pcl[kq - cb] : 0;
        int mx = pk;
        mx = max(mx, __shfl_xor(mx, 16, 64));
        mx = max(mx, __shfl_xor(mx, 32, 64));
        const int nbu = __builtin_amdgcn_readfirstlane((mx + 3) >> 2);
        const int kqc = kq < 511 ? kq : 511;
        const char* lb = (const char*)(nbr + kqc * MAXD);
        h4 acc = {};
        int off = 0;
        for (int g = 0; g < nbu; ++g) {
            unsigned rs0 = *(const unsigned*)(lb + off);
            unsigned rs1 = *(const unsigned*)(lb + off + 4);
            unsigned rs2 = *(const unsigned*)(lb + off + 8);
            unsigned rs3 = *(const unsigned*)(lb + off + 12);
            off += 16;
            union { unsigned u[2]; h4 h; } d0, d1, d2, d3;
            d0.u[0] = deghl[rs0 >> 7]; d0.u[1] = d0.u[0];
            d1.u[0] = deghl[rs1 >> 7]; d1.u[1] = d1.u[0];
            d2.u[0] = deghl[rs2 >> 7]; d2.u[1] = d2.u[0];
            d3.u[0] = deghl[rs3 >> 7]; d3.u[1] = d3.u[0];
            acc += *(const h4*)(g2b + rs0 + lofs) * d0.h;
            acc += *(const h4*)(g2b + rs1 + lofs) * d1.h;
            acc += *(const h4*)(g2b + rs2 + lofs) * d2.h;
            acc += *(const h4*)(g2b + rs3 + lofs) * d3.h;
        }
        const float dk = degl[kqc];
        float val = fmaxf(dk * (float)acc[0], 0.f) * w2v.x
                  + fmaxf(dk * (float)acc[1], 0.f) * w2v.y
                  + fmaxf(dk * (float)acc[2], 0.f) * w2v.z
                  + fmaxf(dk * (float)acc[3], 0.f) * w2v.w;
        #pragma unroll
        for (int mm = 1; mm <= 8; mm <<= 1) val += __shfl_xor(val, mm, 64);
        if ((lane & 15) == 0 && kq < kend) hidt[i * NN + kq] = val;
    }
}

// s[i][j] = 0.5*deg_i[j]*sum_{k in nbr(j), k<i} deg_i[k]*hid[i][k]
// out[i][j] += s; out[j][i] += s.  Over-reads hit phl[r>=i] == 0.
__global__ __launch_bounds__(512) void supp(const unsigned* __restrict__ nbr,
                                            const unsigned char* __restrict__ pcntT,
                                            const float* __restrict__ hidt,
                                            float* __restrict__ out) {
    __shared__ float phl[NN];
    const int i = 511 - (int)blockIdx.x;
    if (i < 1) return;
    const int tid = threadIdx.x;
    const int pc = (int)pcntT[tid * NN + i];
    const float d = (tid < i) ? rsqrtf((float)(pc > 0 ? pc : 1)) : 0.0f;
    phl[tid] = (tid < i) ? d * hidt[i * NN + tid] : 0.0f;
    __syncthreads();
    if (tid < i) {
        const uint4* l4 = (const uint4*)(nbr + tid * MAXD);
        const int nb = (pc + 3) >> 2;
        float s = 0.f;
        for (int b = 0; b < nb; ++b) {
            uint4 qv = l4[b];
            s += phl[qv.x >> 7] + phl[qv.y >> 7] + phl[qv.z >> 7] + phl[qv.w >> 7];
        }
        s *= 0.5f * d;
        out[i * NN + tid] += s;
        out[tid * NN + i] += s;
    }
}

extern "C" void kernel_launch(void* const* d_in, const int* in_sizes, int n_in,
                              void* d_out, int out_size, void* d_ws, size_t ws_size,
                              hipStream_t stream) {
    const float* z   = (const float*)d_in[0];
    const float* adj = (const float*)d_in[1];
    const float* W1  = (const float*)d_in[2];
    const float* W2  = (const float*)d_in[3];
    float* out = (float*)d_out;

    char* wsp = (char*)d_ws;
    unsigned*       nbr   = (unsigned*)      (wsp + 0);
    _Float16*       g16   = (_Float16*)      (wsp + 196608);
    unsigned char*  pcntT = (unsigned char*) (wsp + 262144);
    float*          hidt  = (float*)         (wsp + 524288);

    build_all<<<NN, 512, 0, stream>>>(adj, nbr, pcntT);
    gemm_base<<<16, 256, 0, stream>>>(z, W1, g16);
    hidk<<<dim3(2, NN), 1024, 0, stream>>>(nbr, pcntT, g16, W2, hidt);
    gemm_x<<<dim3(16, 16), 256, 0, stream>>>(z, out);
    supp<<<NN, 512, 0, stream>>>(nbr, pcntT, hidt, out);
}

// Round 7
// 48.501 us; speedup vs baseline: 5.2437x; 1.2362x over previous
//
#include <hip/hip_runtime.h>
#include <hip/hip_bf16.h>

#define NN 512
#define NH 64
#define MAXD 96            // list capacity (deg mean 32, sigma 5.5 -> +11 sigma)
#define ZBYTE (511 * 128)  // sentinel -> byte offset of row 511 (always zeroed: i<=511)

typedef _Float16 h4 __attribute__((ext_vector_type(4)));

// ---------------- ws layout (bytes) ----------------
// nbr  : NN*MAXD*4 = 196608 @ 0        entries = r*128 (byte row offset), sentinel ZBYTE
// g16  : NN*NH*2   = 65536  @ 196608   fp16 z@W1 tile (unscaled)
// pcnt : NN*NN*1   = 262144 @ 262144   u8 pcnt[i][c] = #{r in nbr(c): r < i}  (row per i!)
// total = 524288

// adj symmetric => column c nonzeros == row c nonzeros. One coalesced row read;
// ballot prefix gives BOTH the order-preserving compaction position AND the
// exclusive prefix count (stored as pcnt[i][c] so hid blocks read coalesced).
__global__ __launch_bounds__(512) void build_all(const float* __restrict__ adj,
                                                 unsigned* __restrict__ nbr,
                                                 unsigned char* __restrict__ pcnt) {
    const int c = blockIdx.x;
    const int t = threadIdx.x;
    const int lane = t & 63, w = t >> 6;
    __shared__ int wcnt[8];
    bool f = (adj[c * NN + t] != 0.0f);
    unsigned long long m = __ballot(f);
    int before = __popcll(m & ((1ull << lane) - 1ull));
    if (lane == 0) wcnt[w] = __popcll(m);
    __syncthreads();
    int pre = 0, total = 0;
    #pragma unroll
    for (int j = 0; j < 8; ++j) {
        int x = wcnt[j];
        pre += (j < w) ? x : 0;
        total += x;
    }
    pcnt[t * NN + c] = (unsigned char)(pre + before);   // transposed store
    unsigned* row = nbr + c * MAXD;
    int pos = pre + before;
    if (f && pos < MAXD) row[pos] = (unsigned)(t << 7);
    int m2 = total < MAXD ? total : MAXD;
    for (int j = m2 + t; j < MAXD; j += 512) row[j] = ZBYTE;
}

// Fused: blocks [0,256) -> out = z@z^T (32x32 tiles); blocks [256,272) ->
// g16 = fp16(z @ W1[0:256,0:64]) (32-row slabs). Shared LDS union.
__global__ __launch_bounds__(256) void gemms(const float* __restrict__ z,
                                             const float* __restrict__ W1,
                                             _Float16* __restrict__ g16,
                                             float* __restrict__ out) {
    __shared__ float As[32][34];
    __shared__ float Bs[32][34];
    const int tid = threadIdx.x, tx = tid & 15, ty = tid >> 4;
    const int b = blockIdx.x;
    if (b < 256) {
        const int bi = b >> 4, bj = b & 15;
        float acc[2][2] = {};
        for (int kk = 0; kk < 256; kk += 32) {
            #pragma unroll
            for (int l = 0; l < 4; ++l) {
                int id = tid + (l << 8);
                int m = id >> 5, k = id & 31;
                As[k][m] = z[(bi * 32 + m) * 256 + kk + k];
                Bs[k][m] = z[(bj * 32 + m) * 256 + kk + k];
            }
            __syncthreads();
            #pragma unroll
            for (int k = 0; k < 32; ++k) {
                float2 a = *(const float2*)&As[k][ty * 2];
                float2 bb = *(const float2*)&Bs[k][tx * 2];
                acc[0][0] = fmaf(a.x, bb.x, acc[0][0]);
                acc[0][1] = fmaf(a.x, bb.y, acc[0][1]);
                acc[1][0] = fmaf(a.y, bb.x, acc[1][0]);
                acc[1][1] = fmaf(a.y, bb.y, acc[1][1]);
            }
            __syncthreads();
        }
        #pragma unroll
        for (int p = 0; p < 2; ++p) {
            float2 st = make_float2(acc[p][0], acc[p][1]);
            *(float2*)&out[(bi * 32 + ty * 2 + p) * NN + bj * 32 + tx * 2] = st;
        }
    } else {
        const int bi = b - 256;
        float (*Bsh)[68] = (float(*)[68])&Bs[0][0];   // 16*68=1088 floats == Bs
        float acc[2][4] = {};
        for (int kk = 0; kk < 256; kk += 16) {
            #pragma unroll
            for (int l = 0; l < 2; ++l) {
                int id = tid + (l << 8);
                int m = id >> 4, k = id & 15;
                As[k][m] = z[(bi * 32 + m) * 256 + kk + k];
            }
            #pragma unroll
            for (int l = 0; l < 4; ++l) {
                int id = tid + (l << 8);
                int k = id >> 6, n2 = id & 63;
                Bsh[k][n2] = W1[(kk + k) * 64 + n2];
            }
            __syncthreads();
            #pragma unroll
            for (int k = 0; k < 16; ++k) {
                float2 a = *(const float2*)&As[k][ty * 2];
                float4 bb = *(const float4*)&Bsh[k][tx * 4];
                float ar[2] = {a.x, a.y};
                float br[4] = {bb.x, bb.y, bb.z, bb.w};
                #pragma unroll
                for (int p = 0; p < 2; ++p)
                    #pragma unroll
                    for (int q = 0; q < 4; ++q)
                        acc[p][q] = fmaf(ar[p], br[q], acc[p][q]);
            }
            __syncthreads();
        }
        #pragma unroll
        for (int p = 0; p < 2; ++p) {
            h4 v = {(_Float16)acc[p][0], (_Float16)acc[p][1],
                    (_Float16)acc[p][2], (_Float16)acc[p][3]};
            *(h4*)&g16[(bi * 32 + ty * 2 + p) * NH + tx * 4] = v;
        }
    }
}

// One block per i; 512 blocks x 1024 thr, 68.6KB LDS -> ALL co-resident
// (2 blocks/CU x 256 CU), so per-i work imbalance does not serialize.
// g2[l][h] = deg_i[l]*g16[l][h] (rows >= i zeroed via deg=0) -> masking and
// sentinels are free; inner loop is pure {prefetched list load, ds_read_b64,
// pk_add}. Quarter q of each wave owns one k. Fused supplement at the end.
__global__ __launch_bounds__(1024, 8) void hid_fused(const unsigned* __restrict__ nbr,
                                                     const unsigned char* __restrict__ pcnt,
                                                     const _Float16* __restrict__ g16,
                                                     const float* __restrict__ W2,
                                                     float* __restrict__ out) {
    __shared__ _Float16 g2[NN * NH];   // 64 KB deg-scaled tile
    __shared__ float degl[NN];
    __shared__ float phl[NN];
    __shared__ unsigned char pcl[NN];
    const int i = 511 - (int)blockIdx.x;   // big i first
    if (i < 1) return;
    const int tid = threadIdx.x, lane = tid & 63, w = tid >> 6;

    if (tid < NN) {
        int pc = (int)pcnt[i * NN + tid];            // coalesced 512B row
        pcl[tid] = (unsigned char)pc;
        degl[tid] = (tid < i) ? rsqrtf((float)(pc > 0 ? pc : 1)) : 0.0f;
    }
    __syncthreads();
    {
        const uint4* s = (const uint4*)g16;
        uint4* d = (uint4*)g2;
        #pragma unroll
        for (int u = 0; u < 4; ++u) {
            int t = tid + (u << 10);
            int l = t >> 3;
            uint4 raw = s[t];
            _Float16 dh = (_Float16)degl[l];
            h4 dv = {dh, dh, dh, dh};
            h4 a0 = ((h4*)&raw)[0] * dv;
            h4 a1 = ((h4*)&raw)[1] * dv;
            uint4 o;
            ((h4*)&o)[0] = a0; ((h4*)&o)[1] = a1;
            d[t] = o;
        }
    }
    __syncthreads();

    const int q = lane >> 4;                 // quarter 0..3
    const int lofs = (lane & 15) << 3;       // byte offset within 128B row
    const float4 w2v = *(const float4*)&W2[(lane & 15) << 2];
    const char* g2b = (const char*)g2;

    for (int k0 = (w << 2); k0 < i; k0 += 64) {
        const int kq = k0 + q;
        const int kqc = kq < 511 ? kq : 511;
        int pk = (kq < i) ? (int)pcl[kqc] : 0;
        int mx = max(pk, __shfl_xor(pk, 16, 64));
        mx = max(mx, __shfl_xor(mx, 32, 64));
        const int nbu = __builtin_amdgcn_readfirstlane((mx + 3) >> 2);
        const uint4* l4 = (const uint4*)(nbr + kqc * MAXD);
        h4 acc0 = {}, acc1 = {};
        uint4 e = l4[0];
        for (int g = 0; g < nbu; ++g) {
            uint4 en = l4[g + 1];                    // prefetch (harmless over-read)
            acc0 += *(const h4*)(g2b + (e.x + lofs));
            acc1 += *(const h4*)(g2b + (e.y + lofs));
            acc0 += *(const h4*)(g2b + (e.z + lofs));
            acc1 += *(const h4*)(g2b + (e.w + lofs));
            e = en;
        }
        h4 acc = acc0 + acc1;
        const float dk = degl[kqc];                  // 0 for kq >= i
        float val = fmaxf(dk * (float)acc[0], 0.f) * w2v.x
                  + fmaxf(dk * (float)acc[1], 0.f) * w2v.y
                  + fmaxf(dk * (float)acc[2], 0.f) * w2v.z
                  + fmaxf(dk * (float)acc[3], 0.f) * w2v.w;
        #pragma unroll
        for (int mm = 1; mm <= 8; mm <<= 1) val += __shfl_xor(val, mm, 64);
        if ((lane & 15) == 0 && kq < i) phl[kq] = val;
    }
    __syncthreads();
    if (tid < NN) phl[tid] = (tid < i) ? degl[tid] * phl[tid] : 0.0f;
    __syncthreads();

    if (tid < i) {
        const int pj = (int)pcl[tid];
        const uint4* l4 = (const uint4*)(nbr + tid * MAXD);
        const int nb = (pj + 3) >> 2;
        float s = 0.f;
        for (int b = 0; b < nb; ++b) {
            uint4 qv = l4[b];   // over-read entries land on phl[r>=i] == 0
            s += phl[qv.x >> 7] + phl[qv.y >> 7] + phl[qv.z >> 7] + phl[qv.w >> 7];
        }
        s *= 0.5f * degl[tid];
        out[i * NN + tid] += s;
        out[tid * NN + i] += s;
    }
}

extern "C" void kernel_launch(void* const* d_in, const int* in_sizes, int n_in,
                              void* d_out, int out_size, void* d_ws, size_t ws_size,
                              hipStream_t stream) {
    const float* z   = (const float*)d_in[0];
    const float* adj = (const float*)d_in[1];
    const float* W1  = (const float*)d_in[2];
    const float* W2  = (const float*)d_in[3];
    float* out = (float*)d_out;

    char* wsp = (char*)d_ws;
    unsigned*       nbr  = (unsigned*)      (wsp + 0);
    _Float16*       g16  = (_Float16*)      (wsp + 196608);
    unsigned char*  pcnt = (unsigned char*) (wsp + 262144);

    build_all<<<NN, 512, 0, stream>>>(adj, nbr, pcnt);
    gemms<<<272, 256, 0, stream>>>(z, W1, g16, out);
    hid_fused<<<NN, 1024, 0, stream>>>(nbr, pcnt, g16, W2, out);
}

// Round 9
// 47.546 us; speedup vs baseline: 5.3491x; 1.0201x over previous
//
#include <hip/hip_runtime.h>
#include <hip/hip_bf16.h>

#define NN 512
#define NH 64
#define MAXD 96            // list capacity (deg mean 32, sigma 5.5 -> +11 sigma)
#define ZBYTE (511 * 128)  // sentinel -> byte offset of row 511 (always zeroed: i<=511)

typedef _Float16 h4 __attribute__((ext_vector_type(4)));

// ---------------- ws layout (bytes) ----------------
// nbr  : NN*MAXD*4 = 196608 @ 0        entries = r*128 (byte row offset), sentinel ZBYTE
// g16  : NN*NH*2   = 65536  @ 196608   fp16 z@W1 tile (unscaled)
// pcnt : NN*NN*1   = 262144 @ 262144   u8 pcnt[i][c] = #{r in nbr(c): r < i}
// total = 524288

// K1: 512 blocks x 512 thr. Every block builds the neighbor list + prefix
// counts for column c = b (adj symmetric => row read is the column).
// Independently: blocks 0..255 compute a 32x32 tile of out = z@z^T;
// blocks 256..271 compute a 32-row slab of g16 = fp16(z @ W1[:256]).
// No ordering between the two phases is needed (disjoint in/out).
__global__ __launch_bounds__(512) void build_gemms(const float* __restrict__ adj,
                                                   const float* __restrict__ z,
                                                   const float* __restrict__ W1,
                                                   unsigned* __restrict__ nbr,
                                                   unsigned char* __restrict__ pcnt,
                                                   _Float16* __restrict__ g16,
                                                   float* __restrict__ out) {
    __shared__ float As[32][34];
    __shared__ float Bs[32][34];
    __shared__ int wcnt[8];
    const int b = (int)blockIdx.x;
    const int tid = (int)threadIdx.x;
    const int lane = tid & 63, w = tid >> 6;

    // ---- build lists + pcnt for column c = b ----
    {
        const int c = b;
        bool f = (adj[c * NN + tid] != 0.0f);
        unsigned long long m = __ballot(f);
        int before = __popcll(m & ((1ull << lane) - 1ull));
        if (lane == 0) wcnt[w] = __popcll(m);
        __syncthreads();
        int pre = 0, total = 0;
        #pragma unroll
        for (int j = 0; j < 8; ++j) {
            int x = wcnt[j];
            pre += (j < w) ? x : 0;
            total += x;
        }
        pcnt[tid * NN + c] = (unsigned char)(pre + before);  // pcnt[i][c]
        unsigned* row = nbr + c * MAXD;
        int pos = pre + before;
        if (f && pos < MAXD) row[pos] = (unsigned)(tid << 7);
        int m2 = total < MAXD ? total : MAXD;
        for (int j = m2 + tid; j < MAXD; j += 512) row[j] = ZBYTE;
        __syncthreads();
    }

    const int tx = tid & 15, py = tid >> 4;   // 16 x 32 thread layout
    if (b < 256) {
        // ---- out = z @ z^T, 32x32 tile (bi, bj); 2 outputs/thread ----
        const int bi = b >> 4, bj = b & 15;
        float acc0 = 0.f, acc1 = 0.f;
        for (int kk = 0; kk < 256; kk += 32) {
            #pragma unroll
            for (int l = 0; l < 2; ++l) {
                int id = tid + (l << 9);
                int m = id >> 5, k = id & 31;
                As[k][m] = z[(bi * 32 + m) * 256 + kk + k];
                Bs[k][m] = z[(bj * 32 + m) * 256 + kk + k];
            }
            __syncthreads();
            #pragma unroll
            for (int k = 0; k < 32; ++k) {
                float a = As[k][py];
                float2 bb = *(const float2*)&Bs[k][tx * 2];
                acc0 = fmaf(a, bb.x, acc0);
                acc1 = fmaf(a, bb.y, acc1);
            }
            __syncthreads();
        }
        *(float2*)&out[(bi * 32 + py) * NN + bj * 32 + tx * 2] = make_float2(acc0, acc1);
    } else if (b < 272) {
        // ---- g16 = fp16(z @ W1[:256]), 32-row slab; 4 outputs/thread ----
        const int bi = b - 256;
        float (*As2)[34] = As;
        float (*Bs2)[68] = (float(*)[68])&Bs[0][0];   // 16*68 = 1088 floats == Bs
        float a0 = 0.f, a1 = 0.f, a2 = 0.f, a3 = 0.f;
        for (int kk = 0; kk < 256; kk += 16) {
            {
                int m = tid >> 4, k = tid & 15;       // 32 x 16 = 512
                As2[k][m] = z[(bi * 32 + m) * 256 + kk + k];
            }
            #pragma unroll
            for (int l = 0; l < 2; ++l) {
                int id = tid + (l << 9);
                int k = id >> 6, n2 = id & 63;        // 16 x 64 = 1024
                Bs2[k][n2] = W1[(kk + k) * 64 + n2];
            }
            __syncthreads();
            #pragma unroll
            for (int k = 0; k < 16; ++k) {
                float a = As2[k][py];
                float4 bb = *(const float4*)&Bs2[k][tx * 4];
                a0 = fmaf(a, bb.x, a0);
                a1 = fmaf(a, bb.y, a1);
                a2 = fmaf(a, bb.z, a2);
                a3 = fmaf(a, bb.w, a3);
            }
            __syncthreads();
        }
        h4 v = {(_Float16)a0, (_Float16)a1, (_Float16)a2, (_Float16)a3};
        *(h4*)&g16[(bi * 32 + py) * NH + tx * 4] = v;
    }
}

// K2: one block per i; 512 blocks x 1024 thr, 68.6KB LDS -> all co-resident
// (2/CU). Pairing map i = b<256 ? 511-b : b-256 puts (511-j, j) on one CU
// (HW fills CUs round-robin) -> balanced pair work. g2[l][h] = deg_i[l]*
// g16[l][h] (rows >= i zeroed via deg=0) -> masking & sentinels free.
// Quarter q of each wave owns one k; 2-deep rolling list prefetch.
// Fused supplement scatter at the end.
__global__ __launch_bounds__(1024, 8) void hid_fused(const unsigned* __restrict__ nbr,
                                                     const unsigned char* __restrict__ pcnt,
                                                     const _Float16* __restrict__ g16,
                                                     const float* __restrict__ W2,
                                                     float* __restrict__ out) {
    __shared__ _Float16 g2[NN * NH];   // 64 KB deg-scaled tile
    __shared__ float degl[NN];
    __shared__ float phl[NN];
    __shared__ unsigned char pcl[NN];
    const int b = (int)blockIdx.x;
    const int i = (b < 256) ? (511 - b) : (b - 256);
    if (i < 1) return;
    const int tid = threadIdx.x, lane = tid & 63, w = tid >> 6;

    if (tid < NN) {
        int pc = (int)pcnt[i * NN + tid];            // coalesced 512B row
        pcl[tid] = (unsigned char)pc;
        degl[tid] = (tid < i) ? rsqrtf((float)(pc > 0 ? pc : 1)) : 0.0f;
    }
    __syncthreads();
    {
        const uint4* s = (const uint4*)g16;
        uint4* d = (uint4*)g2;
        #pragma unroll
        for (int u = 0; u < 4; ++u) {
            int t = tid + (u << 10);
            int l = t >> 3;
            uint4 raw = s[t];
            _Float16 dh = (_Float16)degl[l];
            h4 dv = {dh, dh, dh, dh};
            h4 a0 = ((h4*)&raw)[0] * dv;
            h4 a1 = ((h4*)&raw)[1] * dv;
            uint4 o;
            ((h4*)&o)[0] = a0; ((h4*)&o)[1] = a1;
            d[t] = o;
        }
    }
    __syncthreads();

    const int q = lane >> 4;                 // quarter 0..3
    const int lofs = (lane & 15) << 3;       // byte offset within 128B row
    const float4 w2v = *(const float4*)&W2[(lane & 15) << 2];
    const char* g2b = (const char*)g2;

    for (int k0 = (w << 2); k0 < i; k0 += 64) {
        const int kq = k0 + q;
        const int kqc = kq < 511 ? kq : 511;
        int pk = (kq < i) ? (int)pcl[kqc] : 0;
        int mx = max(pk, __shfl_xor(pk, 16, 64));
        mx = max(mx, __shfl_xor(mx, 32, 64));
        const int nbu = __builtin_amdgcn_readfirstlane((mx + 3) >> 2);
        const uint4* l4 = (const uint4*)(nbr + kqc * MAXD);
        h4 acc0 = {}, acc1 = {};
        uint4 e0 = l4[0], e1 = l4[1];        // 2-deep rolling prefetch
        for (int g = 0; g < nbu; ++g) {
            uint4 en = l4[g + 2];            // harmless over-read (stays in ws)
            acc0 += *(const h4*)(g2b + (e0.x + lofs));
            acc1 += *(const h4*)(g2b + (e0.y + lofs));
            acc0 += *(const h4*)(g2b + (e0.z + lofs));
            acc1 += *(const h4*)(g2b + (e0.w + lofs));
            e0 = e1; e1 = en;
        }
        h4 acc = acc0 + acc1;
        const float dk = degl[kqc];          // 0 for kq >= i
        float val = fmaxf(dk * (float)acc[0], 0.f) * w2v.x
                  + fmaxf(dk * (float)acc[1], 0.f) * w2v.y
                  + fmaxf(dk * (float)acc[2], 0.f) * w2v.z
                  + fmaxf(dk * (float)acc[3], 0.f) * w2v.w;
        #pragma unroll
        for (int mm = 1; mm <= 8; mm <<= 1) val += __shfl_xor(val, mm, 64);
        if ((lane & 15) == 0 && kq < i) phl[kq] = val;
    }
    __syncthreads();
    if (tid < NN) phl[tid] = (tid < i) ? degl[tid] * phl[tid] : 0.0f;
    __syncthreads();

    if (tid < i) {
        const int pj = (int)pcl[tid];
        const uint4* l4 = (const uint4*)(nbr + tid * MAXD);
        const int nb = (pj + 3) >> 2;
        float s = 0.f;
        for (int g = 0; g < nb; ++g) {
            uint4 qv = l4[g];   // over-read entries land on phl[r>=i] == 0
            s += phl[qv.x >> 7] + phl[qv.y >> 7] + phl[qv.z >> 7] + phl[qv.w >> 7];
        }
        s *= 0.5f * degl[tid];
        out[i * NN + tid] += s;
        out[tid * NN + i] += s;
    }
}

extern "C" void kernel_launch(void* const* d_in, const int* in_sizes, int n_in,
                              void* d_out, int out_size, void* d_ws, size_t ws_size,
                              hipStream_t stream) {
    const float* z   = (const float*)d_in[0];
    const float* adj = (const float*)d_in[1];
    const float* W1  = (const float*)d_in[2];
    const float* W2  = (const float*)d_in[3];
    float* out = (float*)d_out;

    char* wsp = (char*)d_ws;
    unsigned*       nbr  = (unsigned*)      (wsp + 0);
    _Float16*       g16  = (_Float16*)      (wsp + 196608);
    unsigned char*  pcnt = (unsigned char*) (wsp + 262144);

    build_gemms<<<NN, 512, 0, stream>>>(adj, z, W1, nbr, pcnt, g16, out);
    hid_fused<<<NN, 1024, 0, stream>>>(nbr, pcnt, g16, W2, out);
}

// Round 10
// 47.412 us; speedup vs baseline: 5.3642x; 1.0028x over previous
//
#include <hip/hip_runtime.h>
#include <hip/hip_bf16.h>

#define NN 512
#define NH 64
#define MAXD 96            // list capacity (deg mean 32, sigma 5.5 -> +11 sigma)
#define ZBYTE (511 * 128)  // sentinel -> byte offset of row 511 (deg=0 always zeroes it)

typedef _Float16 h4 __attribute__((ext_vector_type(4)));

// ---------------- ws layout (bytes) ----------------
// nbr  : NN*MAXD*4 = 196608 @ 0        entries = r*128 (byte row offset), sentinel ZBYTE
// g16  : NN*NH*2   = 65536  @ 196608   fp16 z@W1 tile (unscaled)
// pcnt : NN*NN*1   = 262144 @ 262144   u8 pcnt[i][c] = #{r in nbr(c): r < i}
// hidt : NN*NN*4   = 1048576@ 524288   f32 hid[i][k], valid k < i
// total = 1572864

// K1: 512 blocks x 512 thr. Every block builds the neighbor list + prefix
// counts for column c = b. Blocks 0..255 also compute a 32x32 tile of
// out = z@z^T; blocks 256..271 a 32-row slab of g16 = fp16(z @ W1[:256]).
__global__ __launch_bounds__(512) void build_gemms(const float* __restrict__ adj,
                                                   const float* __restrict__ z,
                                                   const float* __restrict__ W1,
                                                   unsigned* __restrict__ nbr,
                                                   unsigned char* __restrict__ pcnt,
                                                   _Float16* __restrict__ g16,
                                                   float* __restrict__ out) {
    __shared__ float As[32][34];
    __shared__ float Bs[32][34];
    __shared__ int wcnt[8];
    const int b = (int)blockIdx.x;
    const int tid = (int)threadIdx.x;
    const int lane = tid & 63, w = tid >> 6;

    {   // build lists + pcnt for column c = b (adj symmetric)
        const int c = b;
        bool f = (adj[c * NN + tid] != 0.0f);
        unsigned long long m = __ballot(f);
        int before = __popcll(m & ((1ull << lane) - 1ull));
        if (lane == 0) wcnt[w] = __popcll(m);
        __syncthreads();
        int pre = 0, total = 0;
        #pragma unroll
        for (int j = 0; j < 8; ++j) {
            int x = wcnt[j];
            pre += (j < w) ? x : 0;
            total += x;
        }
        pcnt[tid * NN + c] = (unsigned char)(pre + before);  // pcnt[i][c]
        unsigned* row = nbr + c * MAXD;
        int pos = pre + before;
        if (f && pos < MAXD) row[pos] = (unsigned)(tid << 7);
        int m2 = total < MAXD ? total : MAXD;
        for (int j = m2 + tid; j < MAXD; j += 512) row[j] = ZBYTE;
        __syncthreads();
    }

    const int tx = tid & 15, py = tid >> 4;   // 16 x 32 thread layout
    if (b < 256) {
        const int bi = b >> 4, bj = b & 15;
        float acc0 = 0.f, acc1 = 0.f;
        for (int kk = 0; kk < 256; kk += 32) {
            #pragma unroll
            for (int l = 0; l < 2; ++l) {
                int id = tid + (l << 9);
                int m = id >> 5, k = id & 31;
                As[k][m] = z[(bi * 32 + m) * 256 + kk + k];
                Bs[k][m] = z[(bj * 32 + m) * 256 + kk + k];
            }
            __syncthreads();
            #pragma unroll
            for (int k = 0; k < 32; ++k) {
                float a = As[k][py];
                float2 bb = *(const float2*)&Bs[k][tx * 2];
                acc0 = fmaf(a, bb.x, acc0);
                acc1 = fmaf(a, bb.y, acc1);
            }
            __syncthreads();
        }
        *(float2*)&out[(bi * 32 + py) * NN + bj * 32 + tx * 2] = make_float2(acc0, acc1);
    } else if (b < 272) {
        const int bi = b - 256;
        float (*As2)[34] = As;
        float (*Bs2)[68] = (float(*)[68])&Bs[0][0];
        float a0 = 0.f, a1 = 0.f, a2 = 0.f, a3 = 0.f;
        for (int kk = 0; kk < 256; kk += 16) {
            {
                int m = tid >> 4, k = tid & 15;
                As2[k][m] = z[(bi * 32 + m) * 256 + kk + k];
            }
            #pragma unroll
            for (int l = 0; l < 2; ++l) {
                int id = tid + (l << 9);
                int k = id >> 6, n2 = id & 63;
                Bs2[k][n2] = W1[(kk + k) * 64 + n2];
            }
            __syncthreads();
            #pragma unroll
            for (int k = 0; k < 16; ++k) {
                float a = As2[k][py];
                float4 bb = *(const float4*)&Bs2[k][tx * 4];
                a0 = fmaf(a, bb.x, a0);
                a1 = fmaf(a, bb.y, a1);
                a2 = fmaf(a, bb.z, a2);
                a3 = fmaf(a, bb.w, a3);
            }
            __syncthreads();
        }
        h4 v = {(_Float16)a0, (_Float16)a1, (_Float16)a2, (_Float16)a3};
        *(h4*)&g16[(bi * 32 + py) * NH + tx * 4] = v;
    }
}

// K2: visit-balanced hid. Grid (3, 512): block (c, b) handles i = 511-b,
// k in [c*i/3, (c+1)*i/3). Work per block <= ~5.4K visits (was 16K at i=511)
// -> near-balanced backfill over the 512 residency slots (2 blocks/CU).
// g2[l][h] = deg_i[l]*g16[l][h] (rows >= i zeroed via deg=0): masking and
// sentinels free. Quarter q of each wave owns one k; 2-deep list prefetch.
__global__ __launch_bounds__(1024, 8) void hidk(const unsigned* __restrict__ nbr,
                                                const unsigned char* __restrict__ pcnt,
                                                const _Float16* __restrict__ g16,
                                                const float* __restrict__ W2,
                                                float* __restrict__ hidt) {
    __shared__ _Float16 g2[NN * NH];   // 64 KB deg-scaled tile
    __shared__ float degl[NN];
    __shared__ unsigned char pcl[NN];
    const int i = 511 - (int)blockIdx.y;   // big i first
    const int c = (int)blockIdx.x;
    const int kc0 = (c * i) / 3, kc1 = ((c + 1) * i) / 3;
    if (kc0 >= kc1) return;
    const int tid = threadIdx.x, lane = tid & 63, w = tid >> 6;

    if (tid < NN) {
        int pc = (int)pcnt[i * NN + tid];            // coalesced 512B row
        pcl[tid] = (unsigned char)pc;
        degl[tid] = (tid < i) ? rsqrtf((float)(pc > 0 ? pc : 1)) : 0.0f;
    }
    __syncthreads();
    {
        const uint4* s = (const uint4*)g16;
        uint4* d = (uint4*)g2;
        #pragma unroll
        for (int u = 0; u < 4; ++u) {
            int t = tid + (u << 10);
            int l = t >> 3;
            uint4 raw = s[t];
            _Float16 dh = (_Float16)degl[l];
            h4 dv = {dh, dh, dh, dh};
            h4 a0 = ((h4*)&raw)[0] * dv;
            h4 a1 = ((h4*)&raw)[1] * dv;
            uint4 o;
            ((h4*)&o)[0] = a0; ((h4*)&o)[1] = a1;
            d[t] = o;
        }
    }
    __syncthreads();

    const int q = lane >> 4;                 // quarter 0..3
    const int lofs = (lane & 15) << 3;       // byte offset within 128B row
    const float4 w2v = *(const float4*)&W2[(lane & 15) << 2];
    const char* g2b = (const char*)g2;

    for (int k0 = kc0 + (w << 2); k0 < kc1; k0 += 64) {
        const int kq = k0 + q;
        const int kqc = kq < 511 ? kq : 511;
        int pk = (kq < kc1) ? (int)pcl[kqc] : 0;
        int mx = max(pk, __shfl_xor(pk, 16, 64));
        mx = max(mx, __shfl_xor(mx, 32, 64));
        const int nbu = __builtin_amdgcn_readfirstlane((mx + 3) >> 2);
        const uint4* l4 = (const uint4*)(nbr + kqc * MAXD);
        h4 acc0 = {}, acc1 = {};
        uint4 e0 = l4[0], e1 = l4[1];        // 2-deep rolling prefetch
        for (int g = 0; g < nbu; ++g) {
            uint4 en = l4[g + 2];            // harmless in-row over-read
            acc0 += *(const h4*)(g2b + (e0.x + lofs));
            acc1 += *(const h4*)(g2b + (e0.y + lofs));
            acc0 += *(const h4*)(g2b + (e0.z + lofs));
            acc1 += *(const h4*)(g2b + (e0.w + lofs));
            e0 = e1; e1 = en;
        }
        h4 acc = acc0 + acc1;
        const float dk = degl[kqc];
        float val = fmaxf(dk * (float)acc[0], 0.f) * w2v.x
                  + fmaxf(dk * (float)acc[1], 0.f) * w2v.y
                  + fmaxf(dk * (float)acc[2], 0.f) * w2v.z
                  + fmaxf(dk * (float)acc[3], 0.f) * w2v.w;
        #pragma unroll
        for (int mm = 1; mm <= 8; mm <<= 1) val += __shfl_xor(val, mm, 64);
        if ((lane & 15) == 0 && kq < kc1) hidt[i * NN + kq] = val;
    }
}

// K3: s[i][j] = 0.5*deg_i[j]*sum_{k in nbr(j), k<i} deg_i[k]*hid[i][k];
// out[i][j] += s; out[j][i] += s. Over-reads hit phl[r>=i] == 0.
__global__ __launch_bounds__(512) void supp(const unsigned* __restrict__ nbr,
                                            const unsigned char* __restrict__ pcnt,
                                            const float* __restrict__ hidt,
                                            float* __restrict__ out) {
    __shared__ float phl[NN];
    const int i = 511 - (int)blockIdx.x;
    if (i < 1) return;
    const int tid = threadIdx.x;
    const int pc = (int)pcnt[i * NN + tid];          // coalesced row
    const float d = (tid < i) ? rsqrtf((float)(pc > 0 ? pc : 1)) : 0.0f;
    phl[tid] = (tid < i) ? d * hidt[i * NN + tid] : 0.0f;
    __syncthreads();
    if (tid < i) {
        const uint4* l4 = (const uint4*)(nbr + tid * MAXD);
        const int nb = (pc + 3) >> 2;
        float s = 0.f;
        for (int g = 0; g < nb; ++g) {
            uint4 qv = l4[g];   // over-read entries land on phl[r>=i] == 0
            s += phl[qv.x >> 7] + phl[qv.y >> 7] + phl[qv.z >> 7] + phl[qv.w >> 7];
        }
        s *= 0.5f * d;
        out[i * NN + tid] += s;
        out[tid * NN + i] += s;
    }
}

extern "C" void kernel_launch(void* const* d_in, const int* in_sizes, int n_in,
                              void* d_out, int out_size, void* d_ws, size_t ws_size,
                              hipStream_t stream) {
    const float* z   = (const float*)d_in[0];
    const float* adj = (const float*)d_in[1];
    const float* W1  = (const float*)d_in[2];
    const float* W2  = (const float*)d_in[3];
    float* out = (float*)d_out;

    char* wsp = (char*)d_ws;
    unsigned*       nbr  = (unsigned*)      (wsp + 0);
    _Float16*       g16  = (_Float16*)      (wsp + 196608);
    unsigned char*  pcnt = (unsigned char*) (wsp + 262144);
    float*          hidt = (float*)         (wsp + 524288);

    build_gemms<<<NN, 512, 0, stream>>>(adj, z, W1, nbr, pcnt, g16, out);
    hidk<<<dim3(3, NN), 1024, 0, stream>>>(nbr, pcnt, g16, W2, hidt);
    supp<<<NN, 512, 0, stream>>>(nbr, pcnt, hidt, out);
}